// Round 10
// baseline (467.109 us; speedup 1.0000x reference)
//
#include <hip/hip_runtime.h>

typedef __bf16 bf16_t;
typedef __bf16 bf16x8 __attribute__((ext_vector_type(8)));
typedef __bf16 bf16x4 __attribute__((ext_vector_type(4)));
typedef float f32x4 __attribute__((ext_vector_type(4)));
typedef float f32x16 __attribute__((ext_vector_type(16)));
typedef unsigned u32x4 __attribute__((ext_vector_type(4)));

#define NTOK 1568
#define CDIM 512
#define BATCH 4
#define MROWS (BATCH*NTOK)  // 6272
#define RSQ1PEPS 0.9999950000374997f
#define CEXP 0.1803368801111204f    // 0.125 * log2(e)
#define DEFER_THR 44.3614195558365f // 8 / CEXP
#define PROWS 200704                // 2 streams *4b *8h *2 splits *1568 q

__device__ __forceinline__ float fexp2(float x) {
  float r;
  asm("v_exp_f32 %0, %1" : "=v"(r) : "v"(x));
  return r;
}

__device__ __forceinline__ void glds16(const bf16_t* src, bf16_t* dst) {
  __builtin_amdgcn_global_load_lds(
      (const __attribute__((address_space(1))) unsigned*)src,
      (__attribute__((address_space(3))) unsigned*)dst, 16, 0, 0);
}

// ---------------- cast all weights f32 -> bf16 (one launch) ----------------
struct CastArgs { const float* s[20]; };
__global__ __launch_bounds__(256) void cast_kernel(CastArgs ca, bf16_t* __restrict__ out) {
  int idx = blockIdx.x * 256 + threadIdx.x;
  int m = idx >> 16;
  const float4* sp = (const float4*)ca.s[m];
  float4 v = sp[idx & 65535];
  bf16x4 o;
  o[0] = (bf16_t)v.x; o[1] = (bf16_t)v.y; o[2] = (bf16_t)v.z; o[3] = (bf16_t)v.w;
  *(bf16x4*)(out + (size_t)idx * 4) = o;
}

// ---------------- tokenize both inputs: x[b][c][s] -> t[b][s][c] ----------------
struct TokArgs { const float* x[2]; float* tf[2]; bf16_t* tb[2]; };
__global__ __launch_bounds__(256) void tok_kernel(TokArgs ta) {
  __shared__ float tile[32][33];
  int z = blockIdx.z, sel = z >> 2, b = z & 3;
  int c0 = blockIdx.y * 32, s0 = blockIdx.x * 32;
  int tx = threadIdx.x, ty = threadIdx.y;
  const float* xp = ta.x[sel] + (size_t)b * CDIM * NTOK;
  for (int r = 0; r < 32; r += 8)
    tile[ty + r][tx] = xp[(size_t)(c0 + ty + r) * NTOK + s0 + tx];
  __syncthreads();
  float* tfp = ta.tf[sel] + (size_t)b * NTOK * CDIM;
  bf16_t* tbp = ta.tb[sel] + (size_t)b * NTOK * CDIM;
  for (int r = 0; r < 32; r += 8) {
    float v = tile[tx][ty + r];
    size_t idx = (size_t)(s0 + ty + r) * CDIM + c0 + tx;
    tfp[idx] = v;
    tbp[idx] = (bf16_t)v;
  }
}

// ---------------- LayerNorm both streams (stage 0 only) ----------------
__global__ __launch_bounds__(64) void ln_kernel(
    const float* __restrict__ t1, const float* __restrict__ t2,
    const float* __restrict__ g1, const float* __restrict__ b1,
    const float* __restrict__ g2, const float* __restrict__ b2,
    bf16_t* __restrict__ o1, bf16_t* __restrict__ o2) {
  int row = blockIdx.x;
  const float* t; const float* g; const float* bt; bf16_t* out;
  if (row < MROWS) { t = t1; g = g1; bt = b1; out = o1; }
  else { row -= MROWS; t = t2; g = g2; bt = b2; out = o2; }
  int l = threadIdx.x;
  const float* x = t + (size_t)row * CDIM;
  float4 v0 = ((const float4*)x)[l];
  float4 v1 = ((const float4*)x)[l + 64];
  float s = v0.x + v0.y + v0.z + v0.w + v1.x + v1.y + v1.z + v1.w;
  float sq = v0.x*v0.x + v0.y*v0.y + v0.z*v0.z + v0.w*v0.w
           + v1.x*v1.x + v1.y*v1.y + v1.z*v1.z + v1.w*v1.w;
  for (int m = 1; m < 64; m <<= 1) { s += __shfl_xor(s, m); sq += __shfl_xor(sq, m); }
  float mean = s * (1.f / 512.f);
  float var = sq * (1.f / 512.f) - mean * mean;
  float rs = rsqrtf(var + 1e-5f);
  float4 g0 = ((const float4*)g)[l], g1v = ((const float4*)g)[l + 64];
  float4 b0 = ((const float4*)bt)[l], b1v = ((const float4*)bt)[l + 64];
  bf16x4 o0, o1v;
  o0[0] = (bf16_t)((v0.x - mean) * rs * g0.x + b0.x);
  o0[1] = (bf16_t)((v0.y - mean) * rs * g0.y + b0.y);
  o0[2] = (bf16_t)((v0.z - mean) * rs * g0.z + b0.z);
  o0[3] = (bf16_t)((v0.w - mean) * rs * g0.w + b0.w);
  o1v[0] = (bf16_t)((v1.x - mean) * rs * g1v.x + b1v.x);
  o1v[1] = (bf16_t)((v1.y - mean) * rs * g1v.y + b1v.y);
  o1v[2] = (bf16_t)((v1.z - mean) * rs * g1v.z + b1v.z);
  o1v[3] = (bf16_t)((v1.w - mean) * rs * g1v.w + b1v.w);
  *(bf16x4*)(out + (size_t)row * CDIM + l * 4) = o0;
  *(bf16x4*)(out + (size_t)row * CDIM + 256 + l * 4) = o1v;
}

// ---------------- shared GEMM core: D = A[M][512] * B[N][512]^T ----------------
template<int MODE>
__device__ __forceinline__ void gemm_core(
    bf16_t (* __restrict__ As)[40], bf16_t (* __restrict__ Bs)[40],
    const bf16_t* __restrict__ A, const bf16_t* __restrict__ Bp,
    const float* __restrict__ bias, const float* __restrict__ bng,
    const float* __restrict__ bnb, bf16_t* __restrict__ outb,
    float* __restrict__ outf, int m0, int n0, int Nvalid) {
  int tid = threadIdx.x;
  int w = tid >> 6, l = tid & 63, lr = l & 15, kg = l >> 4;
  int wm = (w >> 1) * 64, wn = (w & 1) * 64;
  f32x4 acc[4][4];
  for (int i = 0; i < 4; i++)
    for (int j = 0; j < 4; j++)
      acc[i][j] = f32x4{0.f, 0.f, 0.f, 0.f};
  int srow = tid >> 1;
  int soff = (tid & 1) * 16;
  int brow = n0 + srow;
  if (MODE != 0 && brow >= Nvalid) brow = Nvalid - 1;
  const bf16_t* aq = A + (size_t)(m0 + srow) * CDIM + soff;
  const bf16_t* bq = Bp + (size_t)brow * CDIM + soff;
  for (int kk = 0; kk < 16; kk++) {
    __syncthreads();
    bf16x8 a0 = *(const bf16x8*)(aq);
    bf16x8 a1 = *(const bf16x8*)(aq + 8);
    bf16x8 b0 = *(const bf16x8*)(bq);
    bf16x8 b1 = *(const bf16x8*)(bq + 8);
    aq += 32; bq += 32;
    *(bf16x8*)&As[srow][soff] = a0;
    *(bf16x8*)&As[srow][soff + 8] = a1;
    *(bf16x8*)&Bs[srow][soff] = b0;
    *(bf16x8*)&Bs[srow][soff + 8] = b1;
    __syncthreads();
    bf16x8 af[4], bfr[4];
    for (int i = 0; i < 4; i++) af[i] = *(const bf16x8*)&As[wm + i * 16 + lr][kg * 8];
    for (int j = 0; j < 4; j++) bfr[j] = *(const bf16x8*)&Bs[wn + j * 16 + lr][kg * 8];
    for (int i = 0; i < 4; i++)
      for (int j = 0; j < 4; j++)
        acc[i][j] = __builtin_amdgcn_mfma_f32_16x16x32_bf16(af[i], bfr[j], acc[i][j], 0, 0, 0);
  }
  for (int i = 0; i < 4; i++)
    for (int j = 0; j < 4; j++) {
      int rbase = m0 + wm + i * 16 + kg * 4;
      int col = n0 + wn + j * 16 + lr;
      for (int r = 0; r < 4; r++) {
        int row = rbase + r;
        float v = acc[i][j][r];
        if (MODE == 0) {
          v += bias[col];
          outb[(size_t)row * CDIM + col] = (bf16_t)v;
        } else if (MODE == 1) {
          v += bias[row];
          v = v > 0.f ? v : 0.f;
          v *= RSQ1PEPS;
          v = v * bng[row] + bnb[row];
          if (col < Nvalid) outf[(size_t)row * NTOK + col] = v;
        } else {
          v += bias[row];
          if (col < Nvalid) outb[(size_t)row * NTOK + col] = (bf16_t)v;
        }
      }
    }
}

// ---------------- fused per-stage projections ----------------
struct ProjArgs {
  const bf16_t* A0[4]; const bf16_t* W0[4]; const float* b0[4]; bf16_t* o0[4];
  const bf16_t* W2[2]; const bf16_t* B2[2]; const float* b2[2]; bf16_t* o2[2];
};
__global__ __launch_bounds__(256) void proj_kernel(ProjArgs p) {
  __shared__ bf16_t As[128][40];
  __shared__ bf16_t Bs[128][40];
  int id = blockIdx.x;
  if (id < 784) {
    int set = id / 196, rem = id % 196;
    int n0 = (rem & 3) * 128, m0 = (rem >> 2) * 128;
    gemm_core<0>(As, Bs, p.A0[set], p.W0[set], p.b0[set], nullptr, nullptr,
                 p.o0[set], nullptr, m0, n0, 512);
  } else {
    int j = id - 784;
    int unit = j / 52;
    int which = unit >> 2, bat = unit & 3;
    int rem = j % 52;
    int n0 = (rem % 13) * 128, m0 = (rem / 13) * 128;
    gemm_core<2>(As, Bs, p.W2[which], p.B2[which] + (size_t)bat * NTOK * CDIM,
                 p.b2[which], nullptr, nullptr,
                 p.o2[which] + (size_t)bat * CDIM * NTOK, nullptr, m0, n0, NTOK);
  }
}

// ---------------- fused out-heads (MODE 1) ----------------
__global__ __launch_bounds__(256) void head_kernel(
    const bf16_t* __restrict__ W1, const bf16_t* __restrict__ W2,
    const bf16_t* __restrict__ t1b, const bf16_t* __restrict__ t2b,
    const float* __restrict__ b1, const float* __restrict__ b2,
    const float* __restrict__ bng1, const float* __restrict__ bnb1,
    const float* __restrict__ bng2, const float* __restrict__ bnb2,
    float* __restrict__ out) {
  __shared__ bf16_t As[128][40];
  __shared__ bf16_t Bs[128][40];
  int z = blockIdx.z;
  int which = z >> 2, bat = z & 3;
  const bf16_t* A = which ? W2 : W1;
  const bf16_t* Bp = (which ? t2b : t1b) + (size_t)bat * NTOK * CDIM;
  const float* bias = which ? b2 : b1;
  const float* bng = which ? bng2 : bng1;
  const float* bnb = which ? bnb2 : bnb1;
  float* outf = out + (size_t)which * BATCH * CDIM * NTOK + (size_t)bat * CDIM * NTOK;
  int m0 = blockIdx.y * 128, n0 = blockIdx.x * 128;
  gemm_core<1>(As, Bs, A, Bp, bias, bng, bnb, nullptr, outf, m0, n0, NTOK);
}

// ---------------- attention helpers ----------------
__device__ __forceinline__ float tree_max16(const f32x16& s) {
  float a0 = fmaxf(s[0], s[1]), a1 = fmaxf(s[2], s[3]);
  float a2 = fmaxf(s[4], s[5]), a3 = fmaxf(s[6], s[7]);
  float a4 = fmaxf(s[8], s[9]), a5 = fmaxf(s[10], s[11]);
  float a6 = fmaxf(s[12], s[13]), a7 = fmaxf(s[14], s[15]);
  a0 = fmaxf(a0, a1); a2 = fmaxf(a2, a3); a4 = fmaxf(a4, a5); a6 = fmaxf(a6, a7);
  return fmaxf(fmaxf(a0, a2), fmaxf(a4, a6));
}

__device__ __forceinline__ void build_frags(const float* p, bf16x8& Fa, bf16x8& Fb) {
  unsigned pk[8];
#pragma unroll
  for (int g = 0; g < 8; g++) {
    union { bf16_t hh[2]; unsigned u; } cv;
    cv.hh[0] = (bf16_t)p[2 * g];
    cv.hh[1] = (bf16_t)p[2 * g + 1];
    pk[g] = cv.u;
  }
  asm volatile("v_permlane32_swap_b32 %0, %1" : "+v"(pk[0]), "+v"(pk[2]));
  asm volatile("v_permlane32_swap_b32 %0, %1" : "+v"(pk[1]), "+v"(pk[3]));
  asm volatile("v_permlane32_swap_b32 %0, %1" : "+v"(pk[4]), "+v"(pk[6]));
  asm volatile("v_permlane32_swap_b32 %0, %1" : "+v"(pk[5]), "+v"(pk[7]));
  union { u32x4 u; bf16x8 bv; } A, B;
  A.u[0] = pk[0]; A.u[1] = pk[1]; A.u[2] = pk[2]; A.u[3] = pk[3];
  B.u[0] = pk[4]; B.u[1] = pk[5]; B.u[2] = pk[6]; B.u[3] = pk[7];
  Fa = A.bv; Fb = B.bv;
}

// ---------------- attention: KVB=32, ring-4, T15 pipeline, 2-way K-split ----------------
struct AttnArgs {
  const bf16_t* q[2]; const bf16_t* k[2]; const bf16_t* v[2];
};

#define STAGE(TN, SL)                                                         \
  {                                                                           \
    glds16(kgl + (size_t)(TN) * (32 * CDIM), &Ks[SL][wq8][0]);                \
    glds16(vgl + (TN) * 32, &Vs[SL][wq16][0]);                                \
  }

#define QK(SL, SA)                                                            \
  {                                                                           \
    const bf16_t* kr_ = &Ks[SL][lo][0];                                       \
    __builtin_amdgcn_s_setprio(1);                                            \
    SA = __builtin_amdgcn_mfma_f32_32x32x16_bf16(                             \
        *(const bf16x8*)(kr_ + ((hi * 8) ^ sw3)), qf[0], z, 0, 0, 0);         \
    SA = __builtin_amdgcn_mfma_f32_32x32x16_bf16(                             \
        *(const bf16x8*)(kr_ + ((16 + hi * 8) ^ sw3)), qf[1], SA, 0, 0, 0);   \
    SA = __builtin_amdgcn_mfma_f32_32x32x16_bf16(                             \
        *(const bf16x8*)(kr_ + ((32 + hi * 8) ^ sw3)), qf[2], SA, 0, 0, 0);   \
    SA = __builtin_amdgcn_mfma_f32_32x32x16_bf16(                             \
        *(const bf16x8*)(kr_ + ((48 + hi * 8) ^ sw3)), qf[3], SA, 0, 0, 0);   \
    __builtin_amdgcn_s_setprio(0);                                            \
  }

#define FIN(SA, SL)                                                           \
  {                                                                           \
    float tm_ = tree_max16(SA);                                               \
    tm_ = fmaxf(tm_, __shfl_xor(tm_, 32));                                    \
    if (!__all(tm_ <= m_i + DEFER_THR)) {                                     \
      float mn_ = fmaxf(m_i, tm_);                                            \
      float al_ = fexp2((m_i - mn_) * CEXP);                                  \
      _Pragma("unroll")                                                       \
      for (int r_ = 0; r_ < 16; r_++) { ot0[r_] *= al_; ot1[r_] *= al_; }     \
      l_i *= al_;                                                             \
      m_i = mn_;                                                              \
    }                                                                         \
    float nmC_ = -m_i * CEXP;                                                 \
    float pa_[16];                                                            \
    _Pragma("unroll")                                                         \
    for (int r_ = 0; r_ < 16; r_++) pa_[r_] = fexp2(fmaf(SA[r_], CEXP, nmC_));\
    float ts_ = ((pa_[0]+pa_[1])+(pa_[2]+pa_[3]))+((pa_[4]+pa_[5])+(pa_[6]+pa_[7]))\
              + ((pa_[8]+pa_[9])+(pa_[10]+pa_[11]))+((pa_[12]+pa_[13])+(pa_[14]+pa_[15]));\
    ts_ += __shfl_xor(ts_, 32);                                               \
    l_i += ts_;                                                               \
    bf16x8 F0_, F1_;                                                          \
    build_frags(pa_, F0_, F1_);                                               \
    __builtin_amdgcn_s_setprio(1);                                            \
    ot0 = __builtin_amdgcn_mfma_f32_32x32x16_bf16(                            \
        *(const bf16x8*)(&Vs[SL][lo][(hi * 8) ^ sw2]), F0_, ot0, 0, 0, 0);    \
    ot0 = __builtin_amdgcn_mfma_f32_32x32x16_bf16(                            \
        *(const bf16x8*)(&Vs[SL][lo][(16 + hi * 8) ^ sw2]), F1_, ot0, 0, 0, 0);\
    ot1 = __builtin_amdgcn_mfma_f32_32x32x16_bf16(                            \
        *(const bf16x8*)(&Vs[SL][32 + lo][(hi * 8) ^ sw2]), F0_, ot1, 0, 0, 0);\
    ot1 = __builtin_amdgcn_mfma_f32_32x32x16_bf16(                            \
        *(const bf16x8*)(&Vs[SL][32 + lo][(16 + hi * 8) ^ sw2]), F1_, ot1, 0, 0, 0);\
    __builtin_amdgcn_s_setprio(0);                                            \
  }

template<int NT>
__device__ __forceinline__ void attn_core(
    const bf16_t* kgl, const bf16_t* vgl,
    bf16_t (*Ks)[32][64], bf16_t (*Vs)[64][32],
    const bf16x8* qf, int lo, int hi, int sw3, int sw2, int wq8, int wq16,
    float& m_i, float& l_i, f32x16& ot0, f32x16& ot1, const f32x16& z) {
  f32x16 saA, saB;
  STAGE(0, 0);
  STAGE(1, 1);
  STAGE(2, 2);
  asm volatile("s_waitcnt vmcnt(2)" ::: "memory");
  __builtin_amdgcn_s_barrier();
  QK(0, saA);
#pragma unroll
  for (int t = 1; t < NT; ++t) {
    int tn = (t + 2 > NT - 1) ? (NT - 1) : (t + 2);
    STAGE(tn, (t + 2) & 3);
    if (t & 1) { QK(t & 3, saB); FIN(saA, (t - 1) & 3); }
    else       { QK(t & 3, saA); FIN(saB, (t - 1) & 3); }
    asm volatile("s_waitcnt vmcnt(2)" ::: "memory");
    __builtin_amdgcn_s_barrier();
  }
  if ((NT - 1) & 1) { FIN(saB, (NT - 1) & 3); }
  else              { FIN(saA, (NT - 1) & 3); }
}

__global__ __launch_bounds__(256) void attn_kernel(
    AttnArgs aa, bf16_t* __restrict__ po, float* __restrict__ pm,
    float* __restrict__ pl) {
  __shared__ alignas(16) bf16_t Ks[4][32][64];   // 16KB, 3-bit XOR swizzle
  __shared__ alignas(16) bf16_t Vs[4][64][32];   // 8KB,  V^T, 2-bit XOR swizzle
  // XCD-aware decode: all 26 (qt,split) of one (s,b,h) on one XCD
  int id = blockIdx.x;
  int xcd = id & 7, sl = id >> 3;          // sl in 0..207
  int g = xcd + ((sl / 26) << 3);          // group 0..63
  int rem = sl % 26;
  int qt = rem >> 1, sp = rem & 1;
  int ss = g >> 5, b = (g >> 3) & 3, h = g & 7;
  const bf16_t* qg = aa.q[ss];
  const bf16_t* kgp = aa.k[ss];
  const bf16_t* vtg = aa.v[ss];
  int tid = threadIdx.x, w = tid >> 6, l = tid & 63;
  int lo = l & 31, hi = l >> 5;
  int wq8 = w * 8, wq16 = w * 16;
  int sw3 = (lo & 7) << 3, sw2 = (lo & 3) << 3;
  const size_t kbase = ((size_t)b * NTOK) * CDIM + h * 64;
  const size_t vbase = ((size_t)b * CDIM + h * 64) * NTOK;

  int q0 = qt * 128 + w * 32;
  int qrow = q0 + lo;
  int qr = qrow < NTOK ? qrow : NTOK - 1;
  const bf16_t* qp = qg + kbase + (size_t)qr * CDIM + hi * 8;
  bf16x8 qf[4];
  qf[0] = *(const bf16x8*)(qp);
  qf[1] = *(const bf16x8*)(qp + 16);
  qf[2] = *(const bf16x8*)(qp + 32);
  qf[3] = *(const bf16x8*)(qp + 48);
  asm volatile("" : "+v"(qf[0]), "+v"(qf[1]), "+v"(qf[2]), "+v"(qf[3]));
  asm volatile("s_waitcnt vmcnt(0)" ::: "memory");   // drain Q: vmcnt counting exact

  const bf16_t* kgl = kgp + kbase + (size_t)(wq8 + (l >> 3)) * CDIM
                      + (((l & 7) ^ ((l >> 3) & 7)) << 3);
  const bf16_t* vgl = vtg + vbase + (size_t)(wq16 + (l >> 2)) * NTOK
                      + (((l & 3) ^ ((l >> 2) & 3)) << 3);

  float m_i = -3.0e38f, l_i = 0.f;
  f32x16 ot0, ot1, z;
#pragma unroll
  for (int r = 0; r < 16; r++) { ot0[r] = 0.f; ot1[r] = 0.f; z[r] = 0.f; }

  if (sp == 0) {
    attn_core<25>(kgl, vgl, Ks, Vs, qf, lo, hi, sw3, sw2, wq8, wq16,
                  m_i, l_i, ot0, ot1, z);          // tiles 0..24 (keys 0..799)
  } else {
    attn_core<24>(kgl + (size_t)25 * 32 * CDIM, vgl + 25 * 32, Ks, Vs,
                  qf, lo, hi, sw3, sw2, wq8, wq16,
                  m_i, l_i, ot0, ot1, z);          // tiles 25..48 (keys 800..1567)
  }

  if (qrow < NTOK) {
    size_t prow = ((((size_t)ss * 4 + b) * 8 + h) * 2 + sp) * NTOK + qrow;
    bf16_t* pop = po + prow * 64 + hi * 4;
#pragma unroll
    for (int db = 0; db < 2; db++) {
#pragma unroll
      for (int gq = 0; gq < 4; gq++) {
        int doff = db * 32 + gq * 8;
        bf16x4 ob;
        ob[0] = (bf16_t)(db ? ot1[gq * 4 + 0] : ot0[gq * 4 + 0]);
        ob[1] = (bf16_t)(db ? ot1[gq * 4 + 1] : ot0[gq * 4 + 1]);
        ob[2] = (bf16_t)(db ? ot1[gq * 4 + 2] : ot0[gq * 4 + 2]);
        ob[3] = (bf16_t)(db ? ot1[gq * 4 + 3] : ot0[gq * 4 + 3]);
        *(bf16x4*)(pop + doff) = ob;
      }
    }
    if (hi == 0) { pm[prow] = m_i; pl[prow] = l_i; }
  }
}

// ---------------- combine splits + residual + (optional) next-stage LN ----------------
template<bool DOLN>
__global__ __launch_bounds__(256) void combine_kernel(
    const bf16_t* __restrict__ po, const float* __restrict__ pm,
    const float* __restrict__ pl,
    float* __restrict__ t1f, float* __restrict__ t2f,
    bf16_t* __restrict__ t1b, bf16_t* __restrict__ t2b,
    const float* __restrict__ g1, const float* __restrict__ bt1,
    const float* __restrict__ g2, const float* __restrict__ bt2,
    bf16_t* __restrict__ l1b, bf16_t* __restrict__ l2b) {
  int tid = threadIdx.x;
  int r = blockIdx.x * 4 + (tid >> 6);   // row over (s,b,q): 12544 rows
  int l = tid & 63;
  int s = r / (BATCH * NTOK);
  int rem = r - s * (BATCH * NTOK);
  int b = rem / NTOK;
  int q = rem - b * NTOK;
  int h = l >> 3, d0 = (l & 7) * 8;
  size_t p0 = ((((size_t)s * 4 + b) * 8 + h) * 2) * NTOK + q;
  size_t p1 = p0 + NTOK;
  float m0 = pm[p0], m1 = pm[p1];
  float l0 = pl[p0], l1v = pl[p1];
  float mx = fmaxf(m0, m1);
  float w0 = fexp2((m0 - mx) * CEXP);
  float w1 = fexp2((m1 - mx) * CEXP);
  float linv = 1.f / (l0 * w0 + l1v * w1);
  w0 *= linv; w1 *= linv;
  bf16x8 a = *(const bf16x8*)(po + p0 * 64 + d0);
  bf16x8 c = *(const bf16x8*)(po + p1 * 64 + d0);
  size_t tbase = ((size_t)b * NTOK + q) * CDIM + l * 8;
  float* tf = (s ? t2f : t1f) + tbase;
  bf16_t* tb = (s ? t2b : t1b) + tbase;
  float4 o0 = ((float4*)tf)[0], o1 = ((float4*)tf)[1];
  float nv[8];
  nv[0] = o0.x + ((float)a[0] * w0 + (float)c[0] * w1);
  nv[1] = o0.y + ((float)a[1] * w0 + (float)c[1] * w1);
  nv[2] = o0.z + ((float)a[2] * w0 + (float)c[2] * w1);
  nv[3] = o0.w + ((float)a[3] * w0 + (float)c[3] * w1);
  nv[4] = o1.x + ((float)a[4] * w0 + (float)c[4] * w1);
  nv[5] = o1.y + ((float)a[5] * w0 + (float)c[5] * w1);
  nv[6] = o1.z + ((float)a[6] * w0 + (float)c[6] * w1);
  nv[7] = o1.w + ((float)a[7] * w0 + (float)c[7] * w1);
  ((float4*)tf)[0] = float4{nv[0], nv[1], nv[2], nv[3]};
  ((float4*)tf)[1] = float4{nv[4], nv[5], nv[6], nv[7]};
  bf16x8 ob;
#pragma unroll
  for (int j = 0; j < 8; j++) ob[j] = (bf16_t)nv[j];
  *(bf16x8*)tb = ob;
  if (DOLN) {
    float sum = 0.f, sq = 0.f;
#pragma unroll
    for (int j = 0; j < 8; j++) { sum += nv[j]; sq += nv[j] * nv[j]; }
    for (int m = 1; m < 64; m <<= 1) { sum += __shfl_xor(sum, m); sq += __shfl_xor(sq, m); }
    float mean = sum * (1.f / 512.f);
    float var = sq * (1.f / 512.f) - mean * mean;
    float rs = rsqrtf(var + 1e-5f);
    const float* g = s ? g2 : g1;
    const float* bt = s ? bt2 : bt1;
    float4 gv0 = ((const float4*)(g + l * 8))[0], gv1 = ((const float4*)(g + l * 8))[1];
    float4 bv0 = ((const float4*)(bt + l * 8))[0], bv1 = ((const float4*)(bt + l * 8))[1];
    bf16x8 lb;
    lb[0] = (bf16_t)((nv[0] - mean) * rs * gv0.x + bv0.x);
    lb[1] = (bf16_t)((nv[1] - mean) * rs * gv0.y + bv0.y);
    lb[2] = (bf16_t)((nv[2] - mean) * rs * gv0.z + bv0.z);
    lb[3] = (bf16_t)((nv[3] - mean) * rs * gv0.w + bv0.w);
    lb[4] = (bf16_t)((nv[4] - mean) * rs * gv1.x + bv1.x);
    lb[5] = (bf16_t)((nv[5] - mean) * rs * gv1.y + bv1.y);
    lb[6] = (bf16_t)((nv[6] - mean) * rs * gv1.z + bv1.z);
    lb[7] = (bf16_t)((nv[7] - mean) * rs * gv1.w + bv1.w);
    *(bf16x8*)((s ? l2b : l1b) + tbase) = lb;
  }
}

extern "C" void kernel_launch(void* const* d_in, const int* in_sizes, int n_in,
                              void* d_out, int out_size, void* d_ws, size_t ws_size,
                              hipStream_t stream) {
  (void)in_sizes; (void)n_in; (void)out_size; (void)ws_size;
  const float* x1 = (const float*)d_in[0];
  const float* x2 = (const float*)d_in[1];
  const float* Wq1 = (const float*)d_in[2];
  const float* bq1 = (const float*)d_in[3];
  const float* Wk1 = (const float*)d_in[4];
  const float* bk1 = (const float*)d_in[5];
  const float* Wv1 = (const float*)d_in[6];
  const float* bv1 = (const float*)d_in[7];
  const float* ln1_g = (const float*)d_in[8];
  const float* ln1_b = (const float*)d_in[9];
  const float* Wq2 = (const float*)d_in[10];
  const float* bq2 = (const float*)d_in[11];
  const float* Wk2 = (const float*)d_in[12];
  const float* bk2 = (const float*)d_in[13];
  const float* Wv2 = (const float*)d_in[14];
  const float* bv2 = (const float*)d_in[15];
  const float* ln2_g = (const float*)d_in[16];
  const float* ln2_b = (const float*)d_in[17];
  const float* out1_w = (const float*)d_in[18];
  const float* out1_b = (const float*)d_in[19];
  const float* bn1_g = (const float*)d_in[20];
  const float* bn1_b = (const float*)d_in[21];
  const float* out2_w = (const float*)d_in[22];
  const float* out2_b = (const float*)d_in[23];
  const float* bn2_g = (const float*)d_in[24];
  const float* bn2_b = (const float*)d_in[25];

  const size_t WMAT = 512 * 512;
  char* ws = (char*)d_ws;
  bf16_t* wb = (bf16_t*)ws;
  size_t off = 20 * WMAT * sizeof(bf16_t);
  float* t1f = (float*)(ws + off); off += (size_t)MROWS * CDIM * 4;
  float* t2f = (float*)(ws + off); off += (size_t)MROWS * CDIM * 4;
  bf16_t* t1b = (bf16_t*)(ws + off); off += (size_t)MROWS * CDIM * 2;
  bf16_t* t2b = (bf16_t*)(ws + off); off += (size_t)MROWS * CDIM * 2;
  bf16_t* l1b = (bf16_t*)(ws + off); off += (size_t)MROWS * CDIM * 2;
  bf16_t* l2b = (bf16_t*)(ws + off); off += (size_t)MROWS * CDIM * 2;
  bf16_t* q1b = (bf16_t*)(ws + off); off += (size_t)MROWS * CDIM * 2;
  bf16_t* k1b = (bf16_t*)(ws + off); off += (size_t)MROWS * CDIM * 2;
  bf16_t* v1b = (bf16_t*)(ws + off); off += (size_t)MROWS * CDIM * 2;  // V^T [b][512][1568]
  bf16_t* q2b = (bf16_t*)(ws + off); off += (size_t)MROWS * CDIM * 2;
  bf16_t* k2b = (bf16_t*)(ws + off); off += (size_t)MROWS * CDIM * 2;
  bf16_t* v2b = (bf16_t*)(ws + off); off += (size_t)MROWS * CDIM * 2;  // V^T
  bf16_t* po = (bf16_t*)(ws + off); off += (size_t)PROWS * 64 * 2;     // partial O
  float* pm = (float*)(ws + off); off += (size_t)PROWS * 4;
  float* pl = (float*)(ws + off); off += (size_t)PROWS * 4;

  CastArgs ca;
  for (int i = 0; i < 3; i++) {
    ca.s[0 + i] = Wq1 + (size_t)i * WMAT;
    ca.s[3 + i] = Wk1 + (size_t)i * WMAT;
    ca.s[6 + i] = Wv1 + (size_t)i * WMAT;
    ca.s[9 + i] = Wq2 + (size_t)i * WMAT;
    ca.s[12 + i] = Wk2 + (size_t)i * WMAT;
    ca.s[15 + i] = Wv2 + (size_t)i * WMAT;
  }
  ca.s[18] = out1_w;
  ca.s[19] = out2_w;
  cast_kernel<<<5120, 256, 0, stream>>>(ca, wb);

  TokArgs ta;
  ta.x[0] = x1; ta.x[1] = x2;
  ta.tf[0] = t1f; ta.tf[1] = t2f;
  ta.tb[0] = t1b; ta.tb[1] = t2b;
  tok_kernel<<<dim3(49, 16, 8), dim3(32, 8), 0, stream>>>(ta);

  // stage-0 LN (later stages get LN fused into combine)
  ln_kernel<<<2 * MROWS, 64, 0, stream>>>(t1f, t2f,
      ln1_g, ln1_b, ln2_g, ln2_b, l1b, l2b);

  AttnArgs aa;
  aa.q[0] = q1b; aa.q[1] = q2b;
  aa.k[0] = k1b; aa.k[1] = k2b;
  aa.v[0] = v1b; aa.v[1] = v2b;

  for (int i = 0; i < 3; i++) {
    ProjArgs pa;
    pa.A0[0] = l1b; pa.W0[0] = wb + (0 + i) * WMAT; pa.b0[0] = bq1 + i * 512; pa.o0[0] = q1b;
    pa.A0[1] = t2b; pa.W0[1] = wb + (3 + i) * WMAT; pa.b0[1] = bk1 + i * 512; pa.o0[1] = k1b;
    pa.A0[2] = l2b; pa.W0[2] = wb + (9 + i) * WMAT; pa.b0[2] = bq2 + i * 512; pa.o0[2] = q2b;
    pa.A0[3] = t1b; pa.W0[3] = wb + (12 + i) * WMAT; pa.b0[3] = bk2 + i * 512; pa.o0[3] = k2b;
    pa.W2[0] = wb + (6 + i) * WMAT; pa.B2[0] = t2b; pa.b2[0] = bv1 + i * 512; pa.o2[0] = v1b;
    pa.W2[1] = wb + (15 + i) * WMAT; pa.B2[1] = t1b; pa.b2[1] = bv2 + i * 512; pa.o2[1] = v2b;
    proj_kernel<<<1200, 256, 0, stream>>>(pa);
    attn_kernel<<<1664, 256, 0, stream>>>(aa, po, pm, pl);
    if (i < 2) {
      combine_kernel<true><<<3136, 256, 0, stream>>>(po, pm, pl, t1f, t2f, t1b, t2b,
          ln1_g + (i + 1) * 512, ln1_b + (i + 1) * 512,
          ln2_g + (i + 1) * 512, ln2_b + (i + 1) * 512, l1b, l2b);
    } else {
      combine_kernel<false><<<3136, 256, 0, stream>>>(po, pm, pl, t1f, t2f, t1b, t2b,
          nullptr, nullptr, nullptr, nullptr, nullptr, nullptr);
    }
  }

  float* out = (float*)d_out;
  head_kernel<<<dim3(13, 4, 8), 256, 0, stream>>>(
      wb + 18 * WMAT, wb + 19 * WMAT, t1b, t2b,
      out1_b, out2_b, bn1_g, bn1_b, bn2_g, bn2_b, out);
}

// Round 12
// 426.437 us; speedup vs baseline: 1.0954x; 1.0954x over previous
//
#include <hip/hip_runtime.h>

typedef __bf16 bf16_t;
typedef __bf16 bf16x8 __attribute__((ext_vector_type(8)));
typedef __bf16 bf16x4 __attribute__((ext_vector_type(4)));
typedef float f32x4 __attribute__((ext_vector_type(4)));
typedef float f32x16 __attribute__((ext_vector_type(16)));
typedef unsigned u32x4 __attribute__((ext_vector_type(4)));

#define NTOK 1568
#define CDIM 512
#define BATCH 4
#define MROWS (BATCH*NTOK)  // 6272
#define RSQ1PEPS 0.9999950000374997f
#define CEXP 0.1803368801111204f    // 0.125 * log2(e)

__device__ __forceinline__ float fexp2(float x) {
  float r;
  asm("v_exp_f32 %0, %1" : "=v"(r) : "v"(x));
  return r;
}

__device__ __forceinline__ void glds16(const bf16_t* src, bf16_t* dst) {
  __builtin_amdgcn_global_load_lds(
      (const __attribute__((address_space(1))) unsigned*)src,
      (__attribute__((address_space(3))) unsigned*)dst, 16, 0, 0);
}

// ---------------- cast all weights f32 -> bf16 (one launch) ----------------
struct CastArgs { const float* s[20]; };
__global__ __launch_bounds__(256) void cast_kernel(CastArgs ca, bf16_t* __restrict__ out) {
  int idx = blockIdx.x * 256 + threadIdx.x;
  int m = idx >> 16;
  const float4* sp = (const float4*)ca.s[m];
  float4 v = sp[idx & 65535];
  bf16x4 o;
  o[0] = (bf16_t)v.x; o[1] = (bf16_t)v.y; o[2] = (bf16_t)v.z; o[3] = (bf16_t)v.w;
  *(bf16x4*)(out + (size_t)idx * 4) = o;
}

// ---------------- tokenize both inputs: x[b][c][s] -> t[b][s][c] ----------------
struct TokArgs { const float* x[2]; float* tf[2]; bf16_t* tb[2]; };
__global__ __launch_bounds__(256) void tok_kernel(TokArgs ta) {
  __shared__ float tile[32][33];
  int z = blockIdx.z, sel = z >> 2, b = z & 3;
  int c0 = blockIdx.y * 32, s0 = blockIdx.x * 32;
  int tx = threadIdx.x, ty = threadIdx.y;
  const float* xp = ta.x[sel] + (size_t)b * CDIM * NTOK;
  for (int r = 0; r < 32; r += 8)
    tile[ty + r][tx] = xp[(size_t)(c0 + ty + r) * NTOK + s0 + tx];
  __syncthreads();
  float* tfp = ta.tf[sel] + (size_t)b * NTOK * CDIM;
  bf16_t* tbp = ta.tb[sel] + (size_t)b * NTOK * CDIM;
  for (int r = 0; r < 32; r += 8) {
    float v = tile[tx][ty + r];
    size_t idx = (size_t)(s0 + ty + r) * CDIM + c0 + tx;
    tfp[idx] = v;
    tbp[idx] = (bf16_t)v;
  }
}

// ---------------- LayerNorm both streams: f32 in -> bf16 out ----------------
__global__ __launch_bounds__(64) void ln_kernel(
    const float* __restrict__ t1, const float* __restrict__ t2,
    const float* __restrict__ g1, const float* __restrict__ b1,
    const float* __restrict__ g2, const float* __restrict__ b2,
    bf16_t* __restrict__ o1, bf16_t* __restrict__ o2) {
  int row = blockIdx.x;
  const float* t; const float* g; const float* bt; bf16_t* out;
  if (row < MROWS) { t = t1; g = g1; bt = b1; out = o1; }
  else { row -= MROWS; t = t2; g = g2; bt = b2; out = o2; }
  int l = threadIdx.x;
  const float* x = t + (size_t)row * CDIM;
  float4 v0 = ((const float4*)x)[l];
  float4 v1 = ((const float4*)x)[l + 64];
  float s = v0.x + v0.y + v0.z + v0.w + v1.x + v1.y + v1.z + v1.w;
  float sq = v0.x*v0.x + v0.y*v0.y + v0.z*v0.z + v0.w*v0.w
           + v1.x*v1.x + v1.y*v1.y + v1.z*v1.z + v1.w*v1.w;
  for (int m = 1; m < 64; m <<= 1) { s += __shfl_xor(s, m); sq += __shfl_xor(sq, m); }
  float mean = s * (1.f / 512.f);
  float var = sq * (1.f / 512.f) - mean * mean;
  float rs = rsqrtf(var + 1e-5f);
  float4 g0 = ((const float4*)g)[l], g1v = ((const float4*)g)[l + 64];
  float4 b0 = ((const float4*)bt)[l], b1v = ((const float4*)bt)[l + 64];
  bf16x4 o0, o1v;
  o0[0] = (bf16_t)((v0.x - mean) * rs * g0.x + b0.x);
  o0[1] = (bf16_t)((v0.y - mean) * rs * g0.y + b0.y);
  o0[2] = (bf16_t)((v0.z - mean) * rs * g0.z + b0.z);
  o0[3] = (bf16_t)((v0.w - mean) * rs * g0.w + b0.w);
  o1v[0] = (bf16_t)((v1.x - mean) * rs * g1v.x + b1v.x);
  o1v[1] = (bf16_t)((v1.y - mean) * rs * g1v.y + b1v.y);
  o1v[2] = (bf16_t)((v1.z - mean) * rs * g1v.z + b1v.z);
  o1v[3] = (bf16_t)((v1.w - mean) * rs * g1v.w + b1v.w);
  *(bf16x4*)(out + (size_t)row * CDIM + l * 4) = o0;
  *(bf16x4*)(out + (size_t)row * CDIM + 256 + l * 4) = o1v;
}

// ---------------- shared GEMM core: D = A[M][512] * B[N][512]^T ----------------
template<int MODE>
__device__ __forceinline__ void gemm_core(
    bf16_t (* __restrict__ As)[40], bf16_t (* __restrict__ Bs)[40],
    const bf16_t* __restrict__ A, const bf16_t* __restrict__ Bp,
    const float* __restrict__ bias, const float* __restrict__ bng,
    const float* __restrict__ bnb, bf16_t* __restrict__ outb,
    float* __restrict__ outf, int m0, int n0, int Nvalid) {
  int tid = threadIdx.x;
  int w = tid >> 6, l = tid & 63, lr = l & 15, kg = l >> 4;
  int wm = (w >> 1) * 64, wn = (w & 1) * 64;
  f32x4 acc[4][4];
  for (int i = 0; i < 4; i++)
    for (int j = 0; j < 4; j++)
      acc[i][j] = f32x4{0.f, 0.f, 0.f, 0.f};
  int srow = tid >> 1;
  int soff = (tid & 1) * 16;
  int brow = n0 + srow;
  if (MODE != 0 && brow >= Nvalid) brow = Nvalid - 1;
  const bf16_t* aq = A + (size_t)(m0 + srow) * CDIM + soff;
  const bf16_t* bq = Bp + (size_t)brow * CDIM + soff;
  for (int kk = 0; kk < 16; kk++) {
    __syncthreads();
    bf16x8 a0 = *(const bf16x8*)(aq);
    bf16x8 a1 = *(const bf16x8*)(aq + 8);
    bf16x8 b0 = *(const bf16x8*)(bq);
    bf16x8 b1 = *(const bf16x8*)(bq + 8);
    aq += 32; bq += 32;
    *(bf16x8*)&As[srow][soff] = a0;
    *(bf16x8*)&As[srow][soff + 8] = a1;
    *(bf16x8*)&Bs[srow][soff] = b0;
    *(bf16x8*)&Bs[srow][soff + 8] = b1;
    __syncthreads();
    bf16x8 af[4], bfr[4];
    for (int i = 0; i < 4; i++) af[i] = *(const bf16x8*)&As[wm + i * 16 + lr][kg * 8];
    for (int j = 0; j < 4; j++) bfr[j] = *(const bf16x8*)&Bs[wn + j * 16 + lr][kg * 8];
    for (int i = 0; i < 4; i++)
      for (int j = 0; j < 4; j++)
        acc[i][j] = __builtin_amdgcn_mfma_f32_16x16x32_bf16(af[i], bfr[j], acc[i][j], 0, 0, 0);
  }
  for (int i = 0; i < 4; i++)
    for (int j = 0; j < 4; j++) {
      int rbase = m0 + wm + i * 16 + kg * 4;
      int col = n0 + wn + j * 16 + lr;
      for (int r = 0; r < 4; r++) {
        int row = rbase + r;
        float v = acc[i][j][r];
        if (MODE == 0) {
          v += bias[col];
          outb[(size_t)row * CDIM + col] = (bf16_t)v;
        } else if (MODE == 1) {
          v += bias[row];
          v = v > 0.f ? v : 0.f;
          v *= RSQ1PEPS;
          v = v * bng[row] + bnb[row];
          if (col < Nvalid) outf[(size_t)row * NTOK + col] = v;
        } else {
          v += bias[row];
          if (col < Nvalid) outb[(size_t)row * NTOK + col] = (bf16_t)v;
        }
      }
    }
}

// ---------------- fused per-stage projections ----------------
struct ProjArgs {
  const bf16_t* A0[4]; const bf16_t* W0[4]; const float* b0[4]; bf16_t* o0[4];
  const bf16_t* W2[2]; const bf16_t* B2[2]; const float* b2[2]; bf16_t* o2[2];
};
__global__ __launch_bounds__(256) void proj_kernel(ProjArgs p) {
  __shared__ bf16_t As[128][40];
  __shared__ bf16_t Bs[128][40];
  int id = blockIdx.x;
  if (id < 784) {
    int set = id / 196, rem = id % 196;
    int n0 = (rem & 3) * 128, m0 = (rem >> 2) * 128;
    gemm_core<0>(As, Bs, p.A0[set], p.W0[set], p.b0[set], nullptr, nullptr,
                 p.o0[set], nullptr, m0, n0, 512);
  } else {
    int j = id - 784;
    int unit = j / 52;
    int which = unit >> 2, bat = unit & 3;
    int rem = j % 52;
    int n0 = (rem % 13) * 128, m0 = (rem / 13) * 128;
    gemm_core<2>(As, Bs, p.W2[which], p.B2[which] + (size_t)bat * NTOK * CDIM,
                 p.b2[which], nullptr, nullptr,
                 p.o2[which] + (size_t)bat * CDIM * NTOK, nullptr, m0, n0, NTOK);
  }
}

// ---------------- fused out-heads (MODE 1) ----------------
__global__ __launch_bounds__(256) void head_kernel(
    const bf16_t* __restrict__ W1, const bf16_t* __restrict__ W2,
    const bf16_t* __restrict__ t1b, const bf16_t* __restrict__ t2b,
    const float* __restrict__ b1, const float* __restrict__ b2,
    const float* __restrict__ bng1, const float* __restrict__ bnb1,
    const float* __restrict__ bng2, const float* __restrict__ bnb2,
    float* __restrict__ out) {
  __shared__ bf16_t As[128][40];
  __shared__ bf16_t Bs[128][40];
  int z = blockIdx.z;
  int which = z >> 2, bat = z & 3;
  const bf16_t* A = which ? W2 : W1;
  const bf16_t* Bp = (which ? t2b : t1b) + (size_t)bat * NTOK * CDIM;
  const float* bias = which ? b2 : b1;
  const float* bng = which ? bng2 : bng1;
  const float* bnb = which ? bnb2 : bnb1;
  float* outf = out + (size_t)which * BATCH * CDIM * NTOK + (size_t)bat * CDIM * NTOK;
  int m0 = blockIdx.y * 128, n0 = blockIdx.x * 128;
  gemm_core<1>(As, Bs, A, Bp, bias, bng, bnb, nullptr, outf, m0, n0, NTOK);
}

// ---------------- attention helpers ----------------
// build two PV B-fragments (16 keys each) from 16 probabilities via permlane32_swap
__device__ __forceinline__ void build_frags(const float* p, bf16x8& Fa, bf16x8& Fb) {
  unsigned pk[8];
#pragma unroll
  for (int g = 0; g < 8; g++) {
    union { bf16_t hh[2]; unsigned u; } cv;
    cv.hh[0] = (bf16_t)p[2 * g];
    cv.hh[1] = (bf16_t)p[2 * g + 1];
    pk[g] = cv.u;
  }
  asm volatile("v_permlane32_swap_b32 %0, %1" : "+v"(pk[0]), "+v"(pk[2]));
  asm volatile("v_permlane32_swap_b32 %0, %1" : "+v"(pk[1]), "+v"(pk[3]));
  asm volatile("v_permlane32_swap_b32 %0, %1" : "+v"(pk[4]), "+v"(pk[6]));
  asm volatile("v_permlane32_swap_b32 %0, %1" : "+v"(pk[5]), "+v"(pk[7]));
  union { u32x4 u; bf16x8 bv; } A, B;
  A.u[0] = pk[0]; A.u[1] = pk[1]; A.u[2] = pk[2]; A.u[3] = pk[3];
  B.u[0] = pk[4]; B.u[1] = pk[5]; B.u[2] = pk[6]; B.u[3] = pk[7];
  Fa = A.bv; Fb = B.bv;
}

// ---------------- fused attention: KVB=32, ring-4, T15 pipeline, static-max softmax ----------------
struct AttnArgs {
  const bf16_t* q[2]; const bf16_t* k[2]; const bf16_t* v[2];
  float* tf[2]; bf16_t* tb[2];
};

#define STAGE(TN, SL)                                                         \
  {                                                                           \
    int tnS_ = (TN); if (tnS_ > 48) tnS_ = 48;                                \
    glds16(kgl + (size_t)tnS_ * (32 * CDIM), &Ks[SL][wq8][0]);                \
    glds16(vgl + tnS_ * 32, &Vs[SL][wq16][0]);                                \
  }

#define QK(SL, SA)                                                            \
  {                                                                           \
    const bf16_t* kr_ = &Ks[SL][lo][0];                                       \
    __builtin_amdgcn_s_setprio(1);                                            \
    SA = __builtin_amdgcn_mfma_f32_32x32x16_bf16(                             \
        *(const bf16x8*)(kr_ + ((hi * 8) ^ sw3)), qf[0], z, 0, 0, 0);         \
    SA = __builtin_amdgcn_mfma_f32_32x32x16_bf16(                             \
        *(const bf16x8*)(kr_ + ((16 + hi * 8) ^ sw3)), qf[1], SA, 0, 0, 0);   \
    SA = __builtin_amdgcn_mfma_f32_32x32x16_bf16(                             \
        *(const bf16x8*)(kr_ + ((32 + hi * 8) ^ sw3)), qf[2], SA, 0, 0, 0);   \
    SA = __builtin_amdgcn_mfma_f32_32x32x16_bf16(                             \
        *(const bf16x8*)(kr_ + ((48 + hi * 8) ^ sw3)), qf[3], SA, 0, 0, 0);   \
    __builtin_amdgcn_s_setprio(0);                                            \
  }

// static-max softmax finish: p = exp(s/8) directly (softmax shift-invariance,
// scores bounded ⇒ no running max / rescale needed); l_i sums BOTH lane-halves
// (lane l and l^32 each hold 16 of the 32 keys -> cross-half shfl is REQUIRED;
// R11 bug: this line was missing -> wrong denominator)
#define FIN(SA, SL)                                                           \
  {                                                                           \
    float pa_[16];                                                            \
    _Pragma("unroll")                                                         \
    for (int r_ = 0; r_ < 16; r_++) pa_[r_] = fexp2(SA[r_] * CEXP);           \
    float ts_ = ((pa_[0]+pa_[1])+(pa_[2]+pa_[3]))+((pa_[4]+pa_[5])+(pa_[6]+pa_[7]))\
              + ((pa_[8]+pa_[9])+(pa_[10]+pa_[11]))+((pa_[12]+pa_[13])+(pa_[14]+pa_[15]));\
    ts_ += __shfl_xor(ts_, 32);                                               \
    l_i += ts_;                                                               \
    bf16x8 F0_, F1_;                                                          \
    build_frags(pa_, F0_, F1_);                                               \
    __builtin_amdgcn_s_setprio(1);                                            \
    ot0 = __builtin_amdgcn_mfma_f32_32x32x16_bf16(                            \
        *(const bf16x8*)(&Vs[SL][lo][(hi * 8) ^ sw2]), F0_, ot0, 0, 0, 0);    \
    ot0 = __builtin_amdgcn_mfma_f32_32x32x16_bf16(                            \
        *(const bf16x8*)(&Vs[SL][lo][(16 + hi * 8) ^ sw2]), F1_, ot0, 0, 0, 0);\
    ot1 = __builtin_amdgcn_mfma_f32_32x32x16_bf16(                            \
        *(const bf16x8*)(&Vs[SL][32 + lo][(hi * 8) ^ sw2]), F0_, ot1, 0, 0, 0);\
    ot1 = __builtin_amdgcn_mfma_f32_32x32x16_bf16(                            \
        *(const bf16x8*)(&Vs[SL][32 + lo][(16 + hi * 8) ^ sw2]), F1_, ot1, 0, 0, 0);\
    __builtin_amdgcn_s_setprio(0);                                            \
  }

// one pipeline step: stage t+2, QK(t) -> SACUR, finish t-1 from SAPRV, counted wait
#define STEP(T, SACUR, SAPRV, QSL, FSL, SSL)                                  \
  {                                                                           \
    STAGE((T) + 2, SSL);                                                      \
    QK(QSL, SACUR);                                                           \
    FIN(SAPRV, FSL);                                                          \
    asm volatile("s_waitcnt vmcnt(2)" ::: "memory");                          \
    __builtin_amdgcn_s_barrier();                                             \
  }

__global__ __launch_bounds__(256) void attn_kernel(AttnArgs aa) {
  __shared__ alignas(16) bf16_t Ks[4][32][64];   // 16KB, 3-bit XOR swizzle
  __shared__ alignas(16) bf16_t Vs[4][64][32];   // 8KB,  V^T, 2-bit XOR swizzle
  // XCD-aware decode: all 13 q-tiles of one (s,b,h) on one XCD
  int id = blockIdx.x;
  int xcd = id & 7, sl = id >> 3;          // sl in 0..103
  int g = xcd + ((sl / 13) << 3);          // group 0..63
  int qt = sl % 13;
  int ss = g >> 5, b = (g >> 3) & 3, h = g & 7;
  const bf16_t* qg = aa.q[ss];
  const bf16_t* kgp = aa.k[ss];
  const bf16_t* vtg = aa.v[ss];
  float* tf = aa.tf[ss];
  bf16_t* tb = aa.tb[ss];
  int tid = threadIdx.x, w = tid >> 6, l = tid & 63;
  int lo = l & 31, hi = l >> 5;
  int wq8 = w * 8, wq16 = w * 16;
  int sw3 = (lo & 7) << 3, sw2 = (lo & 3) << 3;
  const size_t kbase = ((size_t)b * NTOK) * CDIM + h * 64;
  const size_t vbase = ((size_t)b * CDIM + h * 64) * NTOK;

  int q0 = qt * 128 + w * 32;
  int qrow = q0 + lo;
  int qr = qrow < NTOK ? qrow : NTOK - 1;
  const bf16_t* qp = qg + kbase + (size_t)qr * CDIM + hi * 8;
  bf16x8 qf[4];
  qf[0] = *(const bf16x8*)(qp);
  qf[1] = *(const bf16x8*)(qp + 16);
  qf[2] = *(const bf16x8*)(qp + 32);
  qf[3] = *(const bf16x8*)(qp + 48);
  asm volatile("" : "+v"(qf[0]), "+v"(qf[1]), "+v"(qf[2]), "+v"(qf[3]));
  asm volatile("s_waitcnt vmcnt(0)" ::: "memory");   // drain Q so vmcnt counting is exact

  // staging source addresses (pre-swizzled col-groups)
  const bf16_t* kgl = kgp + kbase + (size_t)(wq8 + (l >> 3)) * CDIM
                      + (((l & 7) ^ ((l >> 3) & 7)) << 3);
  const bf16_t* vgl = vtg + vbase + (size_t)(wq16 + (l >> 2)) * NTOK
                      + (((l & 3) ^ ((l >> 2) & 3)) << 3);

  float l_i = 0.f;
  f32x16 ot0, ot1, z, saA, saB;
#pragma unroll
  for (int r = 0; r < 16; r++) { ot0[r] = 0.f; ot1[r] = 0.f; z[r] = 0.f; }

  // prologue: stage tiles 0,1,2; retire 0,1; compute QK(0)
  STAGE(0, 0);
  STAGE(1, 1);
  STAGE(2, 2);
  asm volatile("s_waitcnt vmcnt(2)" ::: "memory");
  __builtin_amdgcn_s_barrier();
  QK(0, saA);

  // steady loop: steps t=1..48 (12 x 4, residues fixed)
  for (int t = 1; t <= 45; t += 4) {
    STEP(t + 0, saB, saA, 1, 0, 3);
    STEP(t + 1, saA, saB, 2, 1, 0);
    STEP(t + 2, saB, saA, 3, 2, 1);
    STEP(t + 3, saA, saB, 0, 3, 2);
  }
  // finish tile 48 (slot 0)
  FIN(saA, 0);

  if (qrow < NTOK) {
    float inv = 1.f / l_i;
    float* tfp = tf + ((size_t)b * NTOK + qrow) * CDIM + h * 64 + hi * 4;
    bf16_t* tbp = tb + ((size_t)b * NTOK + qrow) * CDIM + h * 64 + hi * 4;
#pragma unroll
    for (int db = 0; db < 2; db++) {
#pragma unroll
      for (int gq = 0; gq < 4; gq++) {
        int doff = db * 32 + gq * 8;
        float4 old = *(float4*)(tfp + doff);
        float4 nv;
        float a0 = (db ? ot1[gq * 4 + 0] : ot0[gq * 4 + 0]) * inv;
        float a1 = (db ? ot1[gq * 4 + 1] : ot0[gq * 4 + 1]) * inv;
        float a2 = (db ? ot1[gq * 4 + 2] : ot0[gq * 4 + 2]) * inv;
        float a3 = (db ? ot1[gq * 4 + 3] : ot0[gq * 4 + 3]) * inv;
        nv.x = old.x + a0; nv.y = old.y + a1; nv.z = old.z + a2; nv.w = old.w + a3;
        *(float4*)(tfp + doff) = nv;
        bf16x4 ob;
        ob[0] = (bf16_t)nv.x; ob[1] = (bf16_t)nv.y;
        ob[2] = (bf16_t)nv.z; ob[3] = (bf16_t)nv.w;
        *(bf16x4*)(tbp + doff) = ob;
      }
    }
  }
}

extern "C" void kernel_launch(void* const* d_in, const int* in_sizes, int n_in,
                              void* d_out, int out_size, void* d_ws, size_t ws_size,
                              hipStream_t stream) {
  (void)in_sizes; (void)n_in; (void)out_size; (void)ws_size;
  const float* x1 = (const float*)d_in[0];
  const float* x2 = (const float*)d_in[1];
  const float* Wq1 = (const float*)d_in[2];
  const float* bq1 = (const float*)d_in[3];
  const float* Wk1 = (const float*)d_in[4];
  const float* bk1 = (const float*)d_in[5];
  const float* Wv1 = (const float*)d_in[6];
  const float* bv1 = (const float*)d_in[7];
  const float* ln1_g = (const float*)d_in[8];
  const float* ln1_b = (const float*)d_in[9];
  const float* Wq2 = (const float*)d_in[10];
  const float* bq2 = (const float*)d_in[11];
  const float* Wk2 = (const float*)d_in[12];
  const float* bk2 = (const float*)d_in[13];
  const float* Wv2 = (const float*)d_in[14];
  const float* bv2 = (const float*)d_in[15];
  const float* ln2_g = (const float*)d_in[16];
  const float* ln2_b = (const float*)d_in[17];
  const float* out1_w = (const float*)d_in[18];
  const float* out1_b = (const float*)d_in[19];
  const float* bn1_g = (const float*)d_in[20];
  const float* bn1_b = (const float*)d_in[21];
  const float* out2_w = (const float*)d_in[22];
  const float* out2_b = (const float*)d_in[23];
  const float* bn2_g = (const float*)d_in[24];
  const float* bn2_b = (const float*)d_in[25];

  const size_t WMAT = 512 * 512;
  char* ws = (char*)d_ws;
  bf16_t* wb = (bf16_t*)ws;
  size_t off = 20 * WMAT * sizeof(bf16_t);
  float* t1f = (float*)(ws + off); off += (size_t)MROWS * CDIM * 4;
  float* t2f = (float*)(ws + off); off += (size_t)MROWS * CDIM * 4;
  bf16_t* t1b = (bf16_t*)(ws + off); off += (size_t)MROWS * CDIM * 2;
  bf16_t* t2b = (bf16_t*)(ws + off); off += (size_t)MROWS * CDIM * 2;
  bf16_t* l1b = (bf16_t*)(ws + off); off += (size_t)MROWS * CDIM * 2;
  bf16_t* l2b = (bf16_t*)(ws + off); off += (size_t)MROWS * CDIM * 2;
  bf16_t* q1b = (bf16_t*)(ws + off); off += (size_t)MROWS * CDIM * 2;
  bf16_t* k1b = (bf16_t*)(ws + off); off += (size_t)MROWS * CDIM * 2;
  bf16_t* v1b = (bf16_t*)(ws + off); off += (size_t)MROWS * CDIM * 2;  // V^T [b][512][1568]
  bf16_t* q2b = (bf16_t*)(ws + off); off += (size_t)MROWS * CDIM * 2;
  bf16_t* k2b = (bf16_t*)(ws + off); off += (size_t)MROWS * CDIM * 2;
  bf16_t* v2b = (bf16_t*)(ws + off); off += (size_t)MROWS * CDIM * 2;  // V^T

  CastArgs ca;
  for (int i = 0; i < 3; i++) {
    ca.s[0 + i] = Wq1 + (size_t)i * WMAT;
    ca.s[3 + i] = Wk1 + (size_t)i * WMAT;
    ca.s[6 + i] = Wv1 + (size_t)i * WMAT;
    ca.s[9 + i] = Wq2 + (size_t)i * WMAT;
    ca.s[12 + i] = Wk2 + (size_t)i * WMAT;
    ca.s[15 + i] = Wv2 + (size_t)i * WMAT;
  }
  ca.s[18] = out1_w;
  ca.s[19] = out2_w;
  cast_kernel<<<5120, 256, 0, stream>>>(ca, wb);

  TokArgs ta;
  ta.x[0] = x1; ta.x[1] = x2;
  ta.tf[0] = t1f; ta.tf[1] = t2f;
  ta.tb[0] = t1b; ta.tb[1] = t2b;
  tok_kernel<<<dim3(49, 16, 8), dim3(32, 8), 0, stream>>>(ta);

  AttnArgs aa;
  aa.q[0] = q1b; aa.q[1] = q2b;
  aa.k[0] = k1b; aa.k[1] = k2b;
  aa.v[0] = v1b; aa.v[1] = v2b;
  aa.tf[0] = t1f; aa.tf[1] = t2f;
  aa.tb[0] = t1b; aa.tb[1] = t2b;

  for (int i = 0; i < 3; i++) {
    ln_kernel<<<2 * MROWS, 64, 0, stream>>>(t1f, t2f,
        ln1_g + i * 512, ln1_b + i * 512, ln2_g + i * 512, ln2_b + i * 512,
        l1b, l2b);
    ProjArgs pa;
    pa.A0[0] = l1b; pa.W0[0] = wb + (0 + i) * WMAT; pa.b0[0] = bq1 + i * 512; pa.o0[0] = q1b;
    pa.A0[1] = t2b; pa.W0[1] = wb + (3 + i) * WMAT; pa.b0[1] = bk1 + i * 512; pa.o0[1] = k1b;
    pa.A0[2] = l2b; pa.W0[2] = wb + (9 + i) * WMAT; pa.b0[2] = bq2 + i * 512; pa.o0[2] = q2b;
    pa.A0[3] = t1b; pa.W0[3] = wb + (12 + i) * WMAT; pa.b0[3] = bk2 + i * 512; pa.o0[3] = k2b;
    pa.W2[0] = wb + (6 + i) * WMAT; pa.B2[0] = t2b; pa.b2[0] = bv1 + i * 512; pa.o2[0] = v1b;
    pa.W2[1] = wb + (15 + i) * WMAT; pa.B2[1] = t1b; pa.b2[1] = bv2 + i * 512; pa.o2[1] = v2b;
    proj_kernel<<<1200, 256, 0, stream>>>(pa);
    attn_kernel<<<832, 256, 0, stream>>>(aa);
  }

  float* out = (float*)d_out;
  head_kernel<<<dim3(13, 4, 8), 256, 0, stream>>>(
      wb + 18 * WMAT, wb + 19 * WMAT, t1b, t2b,
      out1_b, out2_b, bn1_g, bn1_b, bn2_g, bn2_b, out);
}

// Round 13
// 406.666 us; speedup vs baseline: 1.1486x; 1.0486x over previous
//
#include <hip/hip_runtime.h>

typedef __bf16 bf16_t;
typedef __bf16 bf16x8 __attribute__((ext_vector_type(8)));
typedef __bf16 bf16x4 __attribute__((ext_vector_type(4)));
typedef float f32x4 __attribute__((ext_vector_type(4)));
typedef float f32x16 __attribute__((ext_vector_type(16)));
typedef unsigned u32x4 __attribute__((ext_vector_type(4)));

#define NTOK 1568
#define CDIM 512
#define BATCH 4
#define MROWS (BATCH*NTOK)  // 6272
#define RSQ1PEPS 0.9999950000374997f
#define CEXP 0.1803368801111204f    // 0.125 * log2(e), folded into q-projection

__device__ __forceinline__ float fexp2(float x) {
  float r;
  asm("v_exp_f32 %0, %1" : "=v"(r) : "v"(x));
  return r;
}

__device__ __forceinline__ void glds16(const bf16_t* src, bf16_t* dst) {
  __builtin_amdgcn_global_load_lds(
      (const __attribute__((address_space(1))) unsigned*)src,
      (__attribute__((address_space(3))) unsigned*)dst, 16, 0, 0);
}

// ---------------- cast all weights f32 -> bf16 (one launch) ----------------
struct CastArgs { const float* s[20]; };
__global__ __launch_bounds__(256) void cast_kernel(CastArgs ca, bf16_t* __restrict__ out) {
  int idx = blockIdx.x * 256 + threadIdx.x;
  int m = idx >> 16;
  const float4* sp = (const float4*)ca.s[m];
  float4 v = sp[idx & 65535];
  bf16x4 o;
  o[0] = (bf16_t)v.x; o[1] = (bf16_t)v.y; o[2] = (bf16_t)v.z; o[3] = (bf16_t)v.w;
  *(bf16x4*)(out + (size_t)idx * 4) = o;
}

// ---------------- tokenize both inputs: x[b][c][s] -> t[b][s][c] ----------------
struct TokArgs { const float* x[2]; float* tf[2]; bf16_t* tb[2]; };
__global__ __launch_bounds__(256) void tok_kernel(TokArgs ta) {
  __shared__ float tile[32][33];
  int z = blockIdx.z, sel = z >> 2, b = z & 3;
  int c0 = blockIdx.y * 32, s0 = blockIdx.x * 32;
  int tx = threadIdx.x, ty = threadIdx.y;
  const float* xp = ta.x[sel] + (size_t)b * CDIM * NTOK;
  for (int r = 0; r < 32; r += 8)
    tile[ty + r][tx] = xp[(size_t)(c0 + ty + r) * NTOK + s0 + tx];
  __syncthreads();
  float* tfp = ta.tf[sel] + (size_t)b * NTOK * CDIM;
  bf16_t* tbp = ta.tb[sel] + (size_t)b * NTOK * CDIM;
  for (int r = 0; r < 32; r += 8) {
    float v = tile[tx][ty + r];
    size_t idx = (size_t)(s0 + ty + r) * CDIM + c0 + tx;
    tfp[idx] = v;
    tbp[idx] = (bf16_t)v;
  }
}

// ---------------- LayerNorm both streams: f32 in -> bf16 out ----------------
__global__ __launch_bounds__(64) void ln_kernel(
    const float* __restrict__ t1, const float* __restrict__ t2,
    const float* __restrict__ g1, const float* __restrict__ b1,
    const float* __restrict__ g2, const float* __restrict__ b2,
    bf16_t* __restrict__ o1, bf16_t* __restrict__ o2) {
  int row = blockIdx.x;
  const float* t; const float* g; const float* bt; bf16_t* out;
  if (row < MROWS) { t = t1; g = g1; bt = b1; out = o1; }
  else { row -= MROWS; t = t2; g = g2; bt = b2; out = o2; }
  int l = threadIdx.x;
  const float* x = t + (size_t)row * CDIM;
  float4 v0 = ((const float4*)x)[l];
  float4 v1 = ((const float4*)x)[l + 64];
  float s = v0.x + v0.y + v0.z + v0.w + v1.x + v1.y + v1.z + v1.w;
  float sq = v0.x*v0.x + v0.y*v0.y + v0.z*v0.z + v0.w*v0.w
           + v1.x*v1.x + v1.y*v1.y + v1.z*v1.z + v1.w*v1.w;
  for (int m = 1; m < 64; m <<= 1) { s += __shfl_xor(s, m); sq += __shfl_xor(sq, m); }
  float mean = s * (1.f / 512.f);
  float var = sq * (1.f / 512.f) - mean * mean;
  float rs = rsqrtf(var + 1e-5f);
  float4 g0 = ((const float4*)g)[l], g1v = ((const float4*)g)[l + 64];
  float4 b0 = ((const float4*)bt)[l], b1v = ((const float4*)bt)[l + 64];
  bf16x4 o0, o1v;
  o0[0] = (bf16_t)((v0.x - mean) * rs * g0.x + b0.x);
  o0[1] = (bf16_t)((v0.y - mean) * rs * g0.y + b0.y);
  o0[2] = (bf16_t)((v0.z - mean) * rs * g0.z + b0.z);
  o0[3] = (bf16_t)((v0.w - mean) * rs * g0.w + b0.w);
  o1v[0] = (bf16_t)((v1.x - mean) * rs * g1v.x + b1v.x);
  o1v[1] = (bf16_t)((v1.y - mean) * rs * g1v.y + b1v.y);
  o1v[2] = (bf16_t)((v1.z - mean) * rs * g1v.z + b1v.z);
  o1v[3] = (bf16_t)((v1.w - mean) * rs * g1v.w + b1v.w);
  *(bf16x4*)(out + (size_t)row * CDIM + l * 4) = o0;
  *(bf16x4*)(out + (size_t)row * CDIM + 256 + l * 4) = o1v;
}

// ---------------- shared GEMM core: D = A[M][512] * B[N][512]^T ----------------
// MODE 0: bf16 out [row*CDIM+col], (acc+bias[col])*scl. MODE 1: out-head. MODE 2: V^T.
template<int MODE>
__device__ __forceinline__ void gemm_core(
    bf16_t (* __restrict__ As)[40], bf16_t (* __restrict__ Bs)[40],
    const bf16_t* __restrict__ A, const bf16_t* __restrict__ Bp,
    const float* __restrict__ bias, const float* __restrict__ bng,
    const float* __restrict__ bnb, bf16_t* __restrict__ outb,
    float* __restrict__ outf, int m0, int n0, int Nvalid, float scl) {
  int tid = threadIdx.x;
  int w = tid >> 6, l = tid & 63, lr = l & 15, kg = l >> 4;
  int wm = (w >> 1) * 64, wn = (w & 1) * 64;
  f32x4 acc[4][4];
  for (int i = 0; i < 4; i++)
    for (int j = 0; j < 4; j++)
      acc[i][j] = f32x4{0.f, 0.f, 0.f, 0.f};
  int srow = tid >> 1;
  int soff = (tid & 1) * 16;
  int brow = n0 + srow;
  if (MODE != 0 && brow >= Nvalid) brow = Nvalid - 1;
  const bf16_t* aq = A + (size_t)(m0 + srow) * CDIM + soff;
  const bf16_t* bq = Bp + (size_t)brow * CDIM + soff;
  for (int kk = 0; kk < 16; kk++) {
    __syncthreads();
    bf16x8 a0 = *(const bf16x8*)(aq);
    bf16x8 a1 = *(const bf16x8*)(aq + 8);
    bf16x8 b0 = *(const bf16x8*)(bq);
    bf16x8 b1 = *(const bf16x8*)(bq + 8);
    aq += 32; bq += 32;
    *(bf16x8*)&As[srow][soff] = a0;
    *(bf16x8*)&As[srow][soff + 8] = a1;
    *(bf16x8*)&Bs[srow][soff] = b0;
    *(bf16x8*)&Bs[srow][soff + 8] = b1;
    __syncthreads();
    bf16x8 af[4], bfr[4];
    for (int i = 0; i < 4; i++) af[i] = *(const bf16x8*)&As[wm + i * 16 + lr][kg * 8];
    for (int j = 0; j < 4; j++) bfr[j] = *(const bf16x8*)&Bs[wn + j * 16 + lr][kg * 8];
    for (int i = 0; i < 4; i++)
      for (int j = 0; j < 4; j++)
        acc[i][j] = __builtin_amdgcn_mfma_f32_16x16x32_bf16(af[i], bfr[j], acc[i][j], 0, 0, 0);
  }
  for (int i = 0; i < 4; i++)
    for (int j = 0; j < 4; j++) {
      int rbase = m0 + wm + i * 16 + kg * 4;
      int col = n0 + wn + j * 16 + lr;
      for (int r = 0; r < 4; r++) {
        int row = rbase + r;
        float v = acc[i][j][r];
        if (MODE == 0) {
          v = (v + bias[col]) * scl;
          outb[(size_t)row * CDIM + col] = (bf16_t)v;
        } else if (MODE == 1) {
          v += bias[row];
          v = v > 0.f ? v : 0.f;
          v *= RSQ1PEPS;
          v = v * bng[row] + bnb[row];
          if (col < Nvalid) outf[(size_t)row * NTOK + col] = v;
        } else {
          v += bias[row];
          if (col < Nvalid) outb[(size_t)row * NTOK + col] = (bf16_t)v;
        }
      }
    }
}

// ---------------- fused per-stage projections ----------------
struct ProjArgs {
  const bf16_t* A0[4]; const bf16_t* W0[4]; const float* b0[4]; bf16_t* o0[4];
  float scl0[4];
  const bf16_t* W2[2]; const bf16_t* B2[2]; const float* b2[2]; bf16_t* o2[2];
};
__global__ __launch_bounds__(256) void proj_kernel(ProjArgs p) {
  __shared__ bf16_t As[128][40];
  __shared__ bf16_t Bs[128][40];
  int id = blockIdx.x;
  if (id < 784) {
    int set = id / 196, rem = id % 196;
    int n0 = (rem & 3) * 128, m0 = (rem >> 2) * 128;
    gemm_core<0>(As, Bs, p.A0[set], p.W0[set], p.b0[set], nullptr, nullptr,
                 p.o0[set], nullptr, m0, n0, 512, p.scl0[set]);
  } else {
    int j = id - 784;
    int unit = j / 52;
    int which = unit >> 2, bat = unit & 3;
    int rem = j % 52;
    int n0 = (rem % 13) * 128, m0 = (rem / 13) * 128;
    gemm_core<2>(As, Bs, p.W2[which], p.B2[which] + (size_t)bat * NTOK * CDIM,
                 p.b2[which], nullptr, nullptr,
                 p.o2[which] + (size_t)bat * CDIM * NTOK, nullptr, m0, n0, NTOK, 1.f);
  }
}

// ---------------- fused out-heads (MODE 1) ----------------
__global__ __launch_bounds__(256) void head_kernel(
    const bf16_t* __restrict__ W1, const bf16_t* __restrict__ W2,
    const bf16_t* __restrict__ t1b, const bf16_t* __restrict__ t2b,
    const float* __restrict__ b1, const float* __restrict__ b2,
    const float* __restrict__ bng1, const float* __restrict__ bnb1,
    const float* __restrict__ bng2, const float* __restrict__ bnb2,
    float* __restrict__ out) {
  __shared__ bf16_t As[128][40];
  __shared__ bf16_t Bs[128][40];
  int z = blockIdx.z;
  int which = z >> 2, bat = z & 3;
  const bf16_t* A = which ? W2 : W1;
  const bf16_t* Bp = (which ? t2b : t1b) + (size_t)bat * NTOK * CDIM;
  const float* bias = which ? b2 : b1;
  const float* bng = which ? bng2 : bng1;
  const float* bnb = which ? bnb2 : bnb1;
  float* outf = out + (size_t)which * BATCH * CDIM * NTOK + (size_t)bat * CDIM * NTOK;
  int m0 = blockIdx.y * 128, n0 = blockIdx.x * 128;
  gemm_core<1>(As, Bs, A, Bp, bias, bng, bnb, nullptr, outf, m0, n0, NTOK, 1.f);
}

// ---------------- attention helpers ----------------
// build two PV B-fragments (16 keys each) from 16 probabilities via permlane32_swap
__device__ __forceinline__ void build_frags(const float* p, bf16x8& Fa, bf16x8& Fb) {
  unsigned pk[8];
#pragma unroll
  for (int g = 0; g < 8; g++) {
    union { bf16_t hh[2]; unsigned u; } cv;
    cv.hh[0] = (bf16_t)p[2 * g];
    cv.hh[1] = (bf16_t)p[2 * g + 1];
    pk[g] = cv.u;
  }
  asm volatile("v_permlane32_swap_b32 %0, %1" : "+v"(pk[0]), "+v"(pk[2]));
  asm volatile("v_permlane32_swap_b32 %0, %1" : "+v"(pk[1]), "+v"(pk[3]));
  asm volatile("v_permlane32_swap_b32 %0, %1" : "+v"(pk[4]), "+v"(pk[6]));
  asm volatile("v_permlane32_swap_b32 %0, %1" : "+v"(pk[5]), "+v"(pk[7]));
  union { u32x4 u; bf16x8 bv; } A, B;
  A.u[0] = pk[0]; A.u[1] = pk[1]; A.u[2] = pk[2]; A.u[3] = pk[3];
  B.u[0] = pk[4]; B.u[1] = pk[5]; B.u[2] = pk[6]; B.u[3] = pk[7];
  Fa = A.bv; Fb = B.bv;
}

// ---------------- fused attention: KVB=32, ring-4, T15, static-max, MFMA-denominator ----------------
struct AttnArgs {
  const bf16_t* q[2]; const bf16_t* k[2]; const bf16_t* v[2];
  float* tf[2]; bf16_t* tb[2];
};

#define STAGE(TN, SL)                                                         \
  {                                                                           \
    int tnS_ = (TN); if (tnS_ > 48) tnS_ = 48;                                \
    glds16(kgl + (size_t)tnS_ * (32 * CDIM), &Ks[SL][wq8][0]);                \
    glds16(vgl + tnS_ * 32, &Vs[SL][wq16][0]);                                \
  }

#define QK(SL, SA)                                                            \
  {                                                                           \
    const bf16_t* kr_ = &Ks[SL][lo][0];                                       \
    __builtin_amdgcn_s_setprio(1);                                            \
    SA = __builtin_amdgcn_mfma_f32_32x32x16_bf16(                             \
        *(const bf16x8*)(kr_ + ((hi * 8) ^ sw3)), qf[0], z, 0, 0, 0);         \
    SA = __builtin_amdgcn_mfma_f32_32x32x16_bf16(                             \
        *(const bf16x8*)(kr_ + ((16 + hi * 8) ^ sw3)), qf[1], SA, 0, 0, 0);   \
    SA = __builtin_amdgcn_mfma_f32_32x32x16_bf16(                             \
        *(const bf16x8*)(kr_ + ((32 + hi * 8) ^ sw3)), qf[2], SA, 0, 0, 0);   \
    SA = __builtin_amdgcn_mfma_f32_32x32x16_bf16(                             \
        *(const bf16x8*)(kr_ + ((48 + hi * 8) ^ sw3)), qf[3], SA, 0, 0, 0);   \
    __builtin_amdgcn_s_setprio(0);                                            \
  }

// static-max finish: p = exp2(SA) (scale folded into q-proj).
// Denominator via MFMA: ls += ONES·P sums all 32 keys (both lane halves) on the
// matrix pipe -- replaces the VALU sum tree + cross-half shfl entirely.
#define FIN(SA, SL)                                                           \
  {                                                                           \
    float pa_[16];                                                            \
    _Pragma("unroll")                                                         \
    for (int r_ = 0; r_ < 16; r_++) pa_[r_] = fexp2(SA[r_]);                  \
    bf16x8 F0_, F1_;                                                          \
    build_frags(pa_, F0_, F1_);                                               \
    __builtin_amdgcn_s_setprio(1);                                            \
    ls = __builtin_amdgcn_mfma_f32_32x32x16_bf16(kone, F0_, ls, 0, 0, 0);     \
    ls = __builtin_amdgcn_mfma_f32_32x32x16_bf16(kone, F1_, ls, 0, 0, 0);     \
    ot0 = __builtin_amdgcn_mfma_f32_32x32x16_bf16(                            \
        *(const bf16x8*)(&Vs[SL][lo][(hi * 8) ^ sw2]), F0_, ot0, 0, 0, 0);    \
    ot0 = __builtin_amdgcn_mfma_f32_32x32x16_bf16(                            \
        *(const bf16x8*)(&Vs[SL][lo][(16 + hi * 8) ^ sw2]), F1_, ot0, 0, 0, 0);\
    ot1 = __builtin_amdgcn_mfma_f32_32x32x16_bf16(                            \
        *(const bf16x8*)(&Vs[SL][32 + lo][(hi * 8) ^ sw2]), F0_, ot1, 0, 0, 0);\
    ot1 = __builtin_amdgcn_mfma_f32_32x32x16_bf16(                            \
        *(const bf16x8*)(&Vs[SL][32 + lo][(16 + hi * 8) ^ sw2]), F1_, ot1, 0, 0, 0);\
    __builtin_amdgcn_s_setprio(0);                                            \
  }

#define STEP(T, SACUR, SAPRV, QSL, FSL, SSL)                                  \
  {                                                                           \
    STAGE((T) + 2, SSL);                                                      \
    QK(QSL, SACUR);                                                           \
    FIN(SAPRV, FSL);                                                          \
    asm volatile("s_waitcnt vmcnt(2)" ::: "memory");                          \
    __builtin_amdgcn_s_barrier();                                             \
  }

__global__ __launch_bounds__(256) void attn_kernel(AttnArgs aa) {
  __shared__ alignas(16) bf16_t Ks[4][32][64];   // 16KB, 3-bit XOR swizzle
  __shared__ alignas(16) bf16_t Vs[4][64][32];   // 8KB,  V^T, 2-bit XOR swizzle
  // XCD-aware decode: all 13 q-tiles of one (s,b,h) on one XCD
  int id = blockIdx.x;
  int xcd = id & 7, sl = id >> 3;          // sl in 0..103
  int g = xcd + ((sl / 13) << 3);          // group 0..63
  int qt = sl % 13;
  int ss = g >> 5, b = (g >> 3) & 3, h = g & 7;
  const bf16_t* qg = aa.q[ss];
  const bf16_t* kgp = aa.k[ss];
  const bf16_t* vtg = aa.v[ss];
  float* tf = aa.tf[ss];
  bf16_t* tb = aa.tb[ss];
  int tid = threadIdx.x, w = tid >> 6, l = tid & 63;
  int lo = l & 31, hi = l >> 5;
  int wq8 = w * 8, wq16 = w * 16;
  int sw3 = (lo & 7) << 3, sw2 = (lo & 3) << 3;
  const size_t kbase = ((size_t)b * NTOK) * CDIM + h * 64;
  const size_t vbase = ((size_t)b * CDIM + h * 64) * NTOK;

  int q0 = qt * 128 + w * 32;
  int qrow = q0 + lo;
  int qr = qrow < NTOK ? qrow : NTOK - 1;
  const bf16_t* qp = qg + kbase + (size_t)qr * CDIM + hi * 8;
  bf16x8 qf[4];
  qf[0] = *(const bf16x8*)(qp);
  qf[1] = *(const bf16x8*)(qp + 16);
  qf[2] = *(const bf16x8*)(qp + 32);
  qf[3] = *(const bf16x8*)(qp + 48);
  asm volatile("" : "+v"(qf[0]), "+v"(qf[1]), "+v"(qf[2]), "+v"(qf[3]));
  asm volatile("s_waitcnt vmcnt(0)" ::: "memory");   // drain Q so vmcnt counting is exact

  // staging source addresses (pre-swizzled col-groups)
  const bf16_t* kgl = kgp + kbase + (size_t)(wq8 + (l >> 3)) * CDIM
                      + (((l & 7) ^ ((l >> 3) & 7)) << 3);
  const bf16_t* vgl = vtg + vbase + (size_t)(wq16 + (l >> 2)) * NTOK
                      + (((l & 3) ^ ((l >> 2) & 3)) << 3);

  // ones fragment for the denominator MFMA
  bf16x8 kone;
#pragma unroll
  for (int j = 0; j < 8; j++) kone[j] = (bf16_t)1.0f;

  f32x16 ot0, ot1, ls, z, saA, saB;
#pragma unroll
  for (int r = 0; r < 16; r++) { ot0[r] = 0.f; ot1[r] = 0.f; ls[r] = 0.f; z[r] = 0.f; }

  // prologue: stage tiles 0,1,2; retire 0,1; compute QK(0)
  STAGE(0, 0);
  STAGE(1, 1);
  STAGE(2, 2);
  asm volatile("s_waitcnt vmcnt(2)" ::: "memory");
  __builtin_amdgcn_s_barrier();
  QK(0, saA);

  // steady loop: steps t=1..48 (12 x 4, residues fixed)
  for (int t = 1; t <= 45; t += 4) {
    STEP(t + 0, saB, saA, 1, 0, 3);
    STEP(t + 1, saA, saB, 2, 1, 0);
    STEP(t + 2, saB, saA, 3, 2, 1);
    STEP(t + 3, saA, saB, 0, 3, 2);
  }
  // finish tile 48 (slot 0)
  FIN(saA, 0);

  if (qrow < NTOK) {
    float inv = 1.f / ls[0];     // all ls rows identical; lane's col = its q
    float* tfp = tf + ((size_t)b * NTOK + qrow) * CDIM + h * 64 + hi * 4;
    bf16_t* tbp = tb + ((size_t)b * NTOK + qrow) * CDIM + h * 64 + hi * 4;
#pragma unroll
    for (int db = 0; db < 2; db++) {
#pragma unroll
      for (int gq = 0; gq < 4; gq++) {
        int doff = db * 32 + gq * 8;
        float4 old = *(float4*)(tfp + doff);
        float4 nv;
        float a0 = (db ? ot1[gq * 4 + 0] : ot0[gq * 4 + 0]) * inv;
        float a1 = (db ? ot1[gq * 4 + 1] : ot0[gq * 4 + 1]) * inv;
        float a2 = (db ? ot1[gq * 4 + 2] : ot0[gq * 4 + 2]) * inv;
        float a3 = (db ? ot1[gq * 4 + 3] : ot0[gq * 4 + 3]) * inv;
        nv.x = old.x + a0; nv.y = old.y + a1; nv.z = old.z + a2; nv.w = old.w + a3;
        *(float4*)(tfp + doff) = nv;
        bf16x4 ob;
        ob[0] = (bf16_t)nv.x; ob[1] = (bf16_t)nv.y;
        ob[2] = (bf16_t)nv.z; ob[3] = (bf16_t)nv.w;
        *(bf16x4*)(tbp + doff) = ob;
      }
    }
  }
}

extern "C" void kernel_launch(void* const* d_in, const int* in_sizes, int n_in,
                              void* d_out, int out_size, void* d_ws, size_t ws_size,
                              hipStream_t stream) {
  (void)in_sizes; (void)n_in; (void)out_size; (void)ws_size;
  const float* x1 = (const float*)d_in[0];
  const float* x2 = (const float*)d_in[1];
  const float* Wq1 = (const float*)d_in[2];
  const float* bq1 = (const float*)d_in[3];
  const float* Wk1 = (const float*)d_in[4];
  const float* bk1 = (const float*)d_in[5];
  const float* Wv1 = (const float*)d_in[6];
  const float* bv1 = (const float*)d_in[7];
  const float* ln1_g = (const float*)d_in[8];
  const float* ln1_b = (const float*)d_in[9];
  const float* Wq2 = (const float*)d_in[10];
  const float* bq2 = (const float*)d_in[11];
  const float* Wk2 = (const float*)d_in[12];
  const float* bk2 = (const float*)d_in[13];
  const float* Wv2 = (const float*)d_in[14];
  const float* bv2 = (const float*)d_in[15];
  const float* ln2_g = (const float*)d_in[16];
  const float* ln2_b = (const float*)d_in[17];
  const float* out1_w = (const float*)d_in[18];
  const float* out1_b = (const float*)d_in[19];
  const float* bn1_g = (const float*)d_in[20];
  const float* bn1_b = (const float*)d_in[21];
  const float* out2_w = (const float*)d_in[22];
  const float* out2_b = (const float*)d_in[23];
  const float* bn2_g = (const float*)d_in[24];
  const float* bn2_b = (const float*)d_in[25];

  const size_t WMAT = 512 * 512;
  char* ws = (char*)d_ws;
  bf16_t* wb = (bf16_t*)ws;
  size_t off = 20 * WMAT * sizeof(bf16_t);
  float* t1f = (float*)(ws + off); off += (size_t)MROWS * CDIM * 4;
  float* t2f = (float*)(ws + off); off += (size_t)MROWS * CDIM * 4;
  bf16_t* t1b = (bf16_t*)(ws + off); off += (size_t)MROWS * CDIM * 2;
  bf16_t* t2b = (bf16_t*)(ws + off); off += (size_t)MROWS * CDIM * 2;
  bf16_t* l1b = (bf16_t*)(ws + off); off += (size_t)MROWS * CDIM * 2;
  bf16_t* l2b = (bf16_t*)(ws + off); off += (size_t)MROWS * CDIM * 2;
  bf16_t* q1b = (bf16_t*)(ws + off); off += (size_t)MROWS * CDIM * 2;
  bf16_t* k1b = (bf16_t*)(ws + off); off += (size_t)MROWS * CDIM * 2;
  bf16_t* v1b = (bf16_t*)(ws + off); off += (size_t)MROWS * CDIM * 2;  // V^T [b][512][1568]
  bf16_t* q2b = (bf16_t*)(ws + off); off += (size_t)MROWS * CDIM * 2;
  bf16_t* k2b = (bf16_t*)(ws + off); off += (size_t)MROWS * CDIM * 2;
  bf16_t* v2b = (bf16_t*)(ws + off); off += (size_t)MROWS * CDIM * 2;  // V^T

  CastArgs ca;
  for (int i = 0; i < 3; i++) {
    ca.s[0 + i] = Wq1 + (size_t)i * WMAT;
    ca.s[3 + i] = Wk1 + (size_t)i * WMAT;
    ca.s[6 + i] = Wv1 + (size_t)i * WMAT;
    ca.s[9 + i] = Wq2 + (size_t)i * WMAT;
    ca.s[12 + i] = Wk2 + (size_t)i * WMAT;
    ca.s[15 + i] = Wv2 + (size_t)i * WMAT;
  }
  ca.s[18] = out1_w;
  ca.s[19] = out2_w;
  cast_kernel<<<5120, 256, 0, stream>>>(ca, wb);

  TokArgs ta;
  ta.x[0] = x1; ta.x[1] = x2;
  ta.tf[0] = t1f; ta.tf[1] = t2f;
  ta.tb[0] = t1b; ta.tb[1] = t2b;
  tok_kernel<<<dim3(49, 16, 8), dim3(32, 8), 0, stream>>>(ta);

  AttnArgs aa;
  aa.q[0] = q1b; aa.q[1] = q2b;
  aa.k[0] = k1b; aa.k[1] = k2b;
  aa.v[0] = v1b; aa.v[1] = v2b;
  aa.tf[0] = t1f; aa.tf[1] = t2f;
  aa.tb[0] = t1b; aa.tb[1] = t2b;

  for (int i = 0; i < 3; i++) {
    ln_kernel<<<2 * MROWS, 64, 0, stream>>>(t1f, t2f,
        ln1_g + i * 512, ln1_b + i * 512, ln2_g + i * 512, ln2_b + i * 512,
        l1b, l2b);
    ProjArgs pa;
    pa.A0[0] = l1b; pa.W0[0] = wb + (0 + i) * WMAT; pa.b0[0] = bq1 + i * 512; pa.o0[0] = q1b;
    pa.A0[1] = t2b; pa.W0[1] = wb + (3 + i) * WMAT; pa.b0[1] = bk1 + i * 512; pa.o0[1] = k1b;
    pa.A0[2] = l2b; pa.W0[2] = wb + (9 + i) * WMAT; pa.b0[2] = bq2 + i * 512; pa.o0[2] = q2b;
    pa.A0[3] = t1b; pa.W0[3] = wb + (12 + i) * WMAT; pa.b0[3] = bk2 + i * 512; pa.o0[3] = k2b;
    pa.scl0[0] = CEXP; pa.scl0[1] = 1.f; pa.scl0[2] = CEXP; pa.scl0[3] = 1.f;
    pa.W2[0] = wb + (6 + i) * WMAT; pa.B2[0] = t2b; pa.b2[0] = bv1 + i * 512; pa.o2[0] = v1b;
    pa.W2[1] = wb + (15 + i) * WMAT; pa.B2[1] = t1b; pa.b2[1] = bv2 + i * 512; pa.o2[1] = v2b;
    proj_kernel<<<1200, 256, 0, stream>>>(pa);
    attn_kernel<<<832, 256, 0, stream>>>(aa);
  }

  float* out = (float*)d_out;
  head_kernel<<<dim3(13, 4, 8), 256, 0, stream>>>(
      wb + 18 * WMAT, wb + 19 * WMAT, t1b, t2b,
      out1_b, out2_b, bn1_g, bn1_b, bn2_g, bn2_b, out);
}

// Round 14
// 398.023 us; speedup vs baseline: 1.1736x; 1.0217x over previous
//
#include <hip/hip_runtime.h>

typedef __bf16 bf16_t;
typedef __bf16 bf16x8 __attribute__((ext_vector_type(8)));
typedef __bf16 bf16x4 __attribute__((ext_vector_type(4)));
typedef float f32x4 __attribute__((ext_vector_type(4)));
typedef float f32x16 __attribute__((ext_vector_type(16)));
typedef unsigned u32x4 __attribute__((ext_vector_type(4)));

#define NTOK 1568
#define CDIM 512
#define BATCH 4
#define MROWS (BATCH*NTOK)  // 6272
#define RSQ1PEPS 0.9999950000374997f
#define CEXP 0.1803368801111204f    // 0.125 * log2(e), folded into q-projection

__device__ __forceinline__ float fexp2(float x) {
  float r;
  asm("v_exp_f32 %0, %1" : "=v"(r) : "v"(x));
  return r;
}

__device__ __forceinline__ void glds16(const bf16_t* src, bf16_t* dst) {
  __builtin_amdgcn_global_load_lds(
      (const __attribute__((address_space(1))) unsigned*)src,
      (__attribute__((address_space(3))) unsigned*)dst, 16, 0, 0);
}

// ---------------- cast all weights f32 -> bf16 (one launch) ----------------
struct CastArgs { const float* s[20]; };
__global__ __launch_bounds__(256) void cast_kernel(CastArgs ca, bf16_t* __restrict__ out) {
  int idx = blockIdx.x * 256 + threadIdx.x;
  int m = idx >> 16;
  const float4* sp = (const float4*)ca.s[m];
  float4 v = sp[idx & 65535];
  bf16x4 o;
  o[0] = (bf16_t)v.x; o[1] = (bf16_t)v.y; o[2] = (bf16_t)v.z; o[3] = (bf16_t)v.w;
  *(bf16x4*)(out + (size_t)idx * 4) = o;
}

// ---------------- tokenize both inputs: x[b][c][s] -> t[b][s][c] ----------------
struct TokArgs { const float* x[2]; float* tf[2]; bf16_t* tb[2]; };
__global__ __launch_bounds__(256) void tok_kernel(TokArgs ta) {
  __shared__ float tile[32][33];
  int z = blockIdx.z, sel = z >> 2, b = z & 3;
  int c0 = blockIdx.y * 32, s0 = blockIdx.x * 32;
  int tx = threadIdx.x, ty = threadIdx.y;
  const float* xp = ta.x[sel] + (size_t)b * CDIM * NTOK;
  for (int r = 0; r < 32; r += 8)
    tile[ty + r][tx] = xp[(size_t)(c0 + ty + r) * NTOK + s0 + tx];
  __syncthreads();
  float* tfp = ta.tf[sel] + (size_t)b * NTOK * CDIM;
  bf16_t* tbp = ta.tb[sel] + (size_t)b * NTOK * CDIM;
  for (int r = 0; r < 32; r += 8) {
    float v = tile[tx][ty + r];
    size_t idx = (size_t)(s0 + ty + r) * CDIM + c0 + tx;
    tfp[idx] = v;
    tbp[idx] = (bf16_t)v;
  }
}

// ---------------- LayerNorm both streams: f32 in -> bf16 out ----------------
__global__ __launch_bounds__(64) void ln_kernel(
    const float* __restrict__ t1, const float* __restrict__ t2,
    const float* __restrict__ g1, const float* __restrict__ b1,
    const float* __restrict__ g2, const float* __restrict__ b2,
    bf16_t* __restrict__ o1, bf16_t* __restrict__ o2) {
  int row = blockIdx.x;
  const float* t; const float* g; const float* bt; bf16_t* out;
  if (row < MROWS) { t = t1; g = g1; bt = b1; out = o1; }
  else { row -= MROWS; t = t2; g = g2; bt = b2; out = o2; }
  int l = threadIdx.x;
  const float* x = t + (size_t)row * CDIM;
  float4 v0 = ((const float4*)x)[l];
  float4 v1 = ((const float4*)x)[l + 64];
  float s = v0.x + v0.y + v0.z + v0.w + v1.x + v1.y + v1.z + v1.w;
  float sq = v0.x*v0.x + v0.y*v0.y + v0.z*v0.z + v0.w*v0.w
           + v1.x*v1.x + v1.y*v1.y + v1.z*v1.z + v1.w*v1.w;
  for (int m = 1; m < 64; m <<= 1) { s += __shfl_xor(s, m); sq += __shfl_xor(sq, m); }
  float mean = s * (1.f / 512.f);
  float var = sq * (1.f / 512.f) - mean * mean;
  float rs = rsqrtf(var + 1e-5f);
  float4 g0 = ((const float4*)g)[l], g1v = ((const float4*)g)[l + 64];
  float4 b0 = ((const float4*)bt)[l], b1v = ((const float4*)bt)[l + 64];
  bf16x4 o0, o1v;
  o0[0] = (bf16_t)((v0.x - mean) * rs * g0.x + b0.x);
  o0[1] = (bf16_t)((v0.y - mean) * rs * g0.y + b0.y);
  o0[2] = (bf16_t)((v0.z - mean) * rs * g0.z + b0.z);
  o0[3] = (bf16_t)((v0.w - mean) * rs * g0.w + b0.w);
  o1v[0] = (bf16_t)((v1.x - mean) * rs * g1v.x + b1v.x);
  o1v[1] = (bf16_t)((v1.y - mean) * rs * g1v.y + b1v.y);
  o1v[2] = (bf16_t)((v1.z - mean) * rs * g1v.z + b1v.z);
  o1v[3] = (bf16_t)((v1.w - mean) * rs * g1v.w + b1v.w);
  *(bf16x4*)(out + (size_t)row * CDIM + l * 4) = o0;
  *(bf16x4*)(out + (size_t)row * CDIM + 256 + l * 4) = o1v;
}

// ---------------- shared GEMM core: D = A[M][512] * B[N][512]^T ----------------
template<int MODE>
__device__ __forceinline__ void gemm_core(
    bf16_t (* __restrict__ As)[40], bf16_t (* __restrict__ Bs)[40],
    const bf16_t* __restrict__ A, const bf16_t* __restrict__ Bp,
    const float* __restrict__ bias, const float* __restrict__ bng,
    const float* __restrict__ bnb, bf16_t* __restrict__ outb,
    float* __restrict__ outf, int m0, int n0, int Nvalid, float scl) {
  int tid = threadIdx.x;
  int w = tid >> 6, l = tid & 63, lr = l & 15, kg = l >> 4;
  int wm = (w >> 1) * 64, wn = (w & 1) * 64;
  f32x4 acc[4][4];
  for (int i = 0; i < 4; i++)
    for (int j = 0; j < 4; j++)
      acc[i][j] = f32x4{0.f, 0.f, 0.f, 0.f};
  int srow = tid >> 1;
  int soff = (tid & 1) * 16;
  int brow = n0 + srow;
  if (MODE != 0 && brow >= Nvalid) brow = Nvalid - 1;
  const bf16_t* aq = A + (size_t)(m0 + srow) * CDIM + soff;
  const bf16_t* bq = Bp + (size_t)brow * CDIM + soff;
  for (int kk = 0; kk < 16; kk++) {
    __syncthreads();
    bf16x8 a0 = *(const bf16x8*)(aq);
    bf16x8 a1 = *(const bf16x8*)(aq + 8);
    bf16x8 b0 = *(const bf16x8*)(bq);
    bf16x8 b1 = *(const bf16x8*)(bq + 8);
    aq += 32; bq += 32;
    *(bf16x8*)&As[srow][soff] = a0;
    *(bf16x8*)&As[srow][soff + 8] = a1;
    *(bf16x8*)&Bs[srow][soff] = b0;
    *(bf16x8*)&Bs[srow][soff + 8] = b1;
    __syncthreads();
    bf16x8 af[4], bfr[4];
    for (int i = 0; i < 4; i++) af[i] = *(const bf16x8*)&As[wm + i * 16 + lr][kg * 8];
    for (int j = 0; j < 4; j++) bfr[j] = *(const bf16x8*)&Bs[wn + j * 16 + lr][kg * 8];
    for (int i = 0; i < 4; i++)
      for (int j = 0; j < 4; j++)
        acc[i][j] = __builtin_amdgcn_mfma_f32_16x16x32_bf16(af[i], bfr[j], acc[i][j], 0, 0, 0);
  }
  for (int i = 0; i < 4; i++)
    for (int j = 0; j < 4; j++) {
      int rbase = m0 + wm + i * 16 + kg * 4;
      int col = n0 + wn + j * 16 + lr;
      for (int r = 0; r < 4; r++) {
        int row = rbase + r;
        float v = acc[i][j][r];
        if (MODE == 0) {
          v = (v + bias[col]) * scl;
          outb[(size_t)row * CDIM + col] = (bf16_t)v;
        } else if (MODE == 1) {
          v += bias[row];
          v = v > 0.f ? v : 0.f;
          v *= RSQ1PEPS;
          v = v * bng[row] + bnb[row];
          if (col < Nvalid) outf[(size_t)row * NTOK + col] = v;
        } else {
          v += bias[row];
          if (col < Nvalid) outb[(size_t)row * NTOK + col] = (bf16_t)v;
        }
      }
    }
}

// ---------------- fused per-stage projections ----------------
struct ProjArgs {
  const bf16_t* A0[4]; const bf16_t* W0[4]; const float* b0[4]; bf16_t* o0[4];
  float scl0[4];
  const bf16_t* W2[2]; const bf16_t* B2[2]; const float* b2[2]; bf16_t* o2[2];
};
__global__ __launch_bounds__(256) void proj_kernel(ProjArgs p) {
  __shared__ bf16_t As[128][40];
  __shared__ bf16_t Bs[128][40];
  int id = blockIdx.x;
  if (id < 784) {
    int set = id / 196, rem = id % 196;
    int n0 = (rem & 3) * 128, m0 = (rem >> 2) * 128;
    gemm_core<0>(As, Bs, p.A0[set], p.W0[set], p.b0[set], nullptr, nullptr,
                 p.o0[set], nullptr, m0, n0, 512, p.scl0[set]);
  } else {
    int j = id - 784;
    int unit = j / 52;
    int which = unit >> 2, bat = unit & 3;
    int rem = j % 52;
    int n0 = (rem % 13) * 128, m0 = (rem / 13) * 128;
    gemm_core<2>(As, Bs, p.W2[which], p.B2[which] + (size_t)bat * NTOK * CDIM,
                 p.b2[which], nullptr, nullptr,
                 p.o2[which] + (size_t)bat * CDIM * NTOK, nullptr, m0, n0, NTOK, 1.f);
  }
}

// ---------------- fused out-heads (MODE 1) ----------------
__global__ __launch_bounds__(256) void head_kernel(
    const bf16_t* __restrict__ W1, const bf16_t* __restrict__ W2,
    const bf16_t* __restrict__ t1b, const bf16_t* __restrict__ t2b,
    const float* __restrict__ b1, const float* __restrict__ b2,
    const float* __restrict__ bng1, const float* __restrict__ bnb1,
    const float* __restrict__ bng2, const float* __restrict__ bnb2,
    float* __restrict__ out) {
  __shared__ bf16_t As[128][40];
  __shared__ bf16_t Bs[128][40];
  int z = blockIdx.z;
  int which = z >> 2, bat = z & 3;
  const bf16_t* A = which ? W2 : W1;
  const bf16_t* Bp = (which ? t2b : t1b) + (size_t)bat * NTOK * CDIM;
  const float* bias = which ? b2 : b1;
  const float* bng = which ? bng2 : bng1;
  const float* bnb = which ? bnb2 : bnb1;
  float* outf = out + (size_t)which * BATCH * CDIM * NTOK + (size_t)bat * CDIM * NTOK;
  int m0 = blockIdx.y * 128, n0 = blockIdx.x * 128;
  gemm_core<1>(As, Bs, A, Bp, bias, bng, bnb, nullptr, outf, m0, n0, NTOK, 1.f);
}

// ---------------- attention helpers ----------------
// build two PV B-fragments (16 keys each) from 16 probabilities via permlane32_swap
__device__ __forceinline__ void build_frags(const float* p, bf16x8& Fa, bf16x8& Fb) {
  unsigned pk[8];
#pragma unroll
  for (int g = 0; g < 8; g++) {
    union { bf16_t hh[2]; unsigned u; } cv;
    cv.hh[0] = (bf16_t)p[2 * g];
    cv.hh[1] = (bf16_t)p[2 * g + 1];
    pk[g] = cv.u;
  }
  asm volatile("v_permlane32_swap_b32 %0, %1" : "+v"(pk[0]), "+v"(pk[2]));
  asm volatile("v_permlane32_swap_b32 %0, %1" : "+v"(pk[1]), "+v"(pk[3]));
  asm volatile("v_permlane32_swap_b32 %0, %1" : "+v"(pk[4]), "+v"(pk[6]));
  asm volatile("v_permlane32_swap_b32 %0, %1" : "+v"(pk[5]), "+v"(pk[7]));
  union { u32x4 u; bf16x8 bv; } A, B;
  A.u[0] = pk[0]; A.u[1] = pk[1]; A.u[2] = pk[2]; A.u[3] = pk[3];
  B.u[0] = pk[4]; B.u[1] = pk[5]; B.u[2] = pk[6]; B.u[3] = pk[7];
  Fa = A.bv; Fb = B.bv;
}

// ---------------- fused attention: KVB=32, ring-4, T15, static-max, MFMA-denominator ----------------
struct AttnArgs {
  const bf16_t* q[2]; const bf16_t* k[2]; const bf16_t* v[2];
  float* tf[2]; bf16_t* tb[2];
};

#define STAGE(TN, SL)                                                         \
  {                                                                           \
    int tnS_ = (TN); if (tnS_ > 48) tnS_ = 48;                                \
    glds16(kgl + (size_t)tnS_ * (32 * CDIM), &Ks[SL][wq8][0]);                \
    glds16(vgl + tnS_ * 32, &Vs[SL][wq16][0]);                                \
  }

#define QK(SL, SA)                                                            \
  {                                                                           \
    const bf16_t* kr_ = &Ks[SL][lo][0];                                       \
    __builtin_amdgcn_s_setprio(1);                                            \
    SA = __builtin_amdgcn_mfma_f32_32x32x16_bf16(                             \
        *(const bf16x8*)(kr_ + ((hi * 8) ^ sw3)), qf[0], z, 0, 0, 0);         \
    SA = __builtin_amdgcn_mfma_f32_32x32x16_bf16(                             \
        *(const bf16x8*)(kr_ + ((16 + hi * 8) ^ sw3)), qf[1], SA, 0, 0, 0);   \
    SA = __builtin_amdgcn_mfma_f32_32x32x16_bf16(                             \
        *(const bf16x8*)(kr_ + ((32 + hi * 8) ^ sw3)), qf[2], SA, 0, 0, 0);   \
    SA = __builtin_amdgcn_mfma_f32_32x32x16_bf16(                             \
        *(const bf16x8*)(kr_ + ((48 + hi * 8) ^ sw3)), qf[3], SA, 0, 0, 0);   \
    __builtin_amdgcn_s_setprio(0);                                            \
  }

// static-max finish: p = exp2(SA) (scale folded into q-proj).
// Denominator via MFMA (ones row). V swizzle sw2 = ((lo>>1)&3)<<3 spreads the
// 64-lane b128 reads uniformly over all 8 bank-quads (row-parity + 2 swizzle
// bits) -> conflict-free; old (lo&3) collapsed 32 lanes onto 4 slots (8-way).
#define FIN(SA, SL)                                                           \
  {                                                                           \
    float pa_[16];                                                            \
    _Pragma("unroll")                                                         \
    for (int r_ = 0; r_ < 16; r_++) pa_[r_] = fexp2(SA[r_]);                  \
    bf16x8 F0_, F1_;                                                          \
    build_frags(pa_, F0_, F1_);                                               \
    __builtin_amdgcn_s_setprio(1);                                            \
    ls = __builtin_amdgcn_mfma_f32_32x32x16_bf16(kone, F0_, ls, 0, 0, 0);     \
    ls = __builtin_amdgcn_mfma_f32_32x32x16_bf16(kone, F1_, ls, 0, 0, 0);     \
    ot0 = __builtin_amdgcn_mfma_f32_32x32x16_bf16(                            \
        *(const bf16x8*)(&Vs[SL][lo][(hi * 8) ^ sw2]), F0_, ot0, 0, 0, 0);    \
    ot0 = __builtin_amdgcn_mfma_f32_32x32x16_bf16(                            \
        *(const bf16x8*)(&Vs[SL][lo][(16 + hi * 8) ^ sw2]), F1_, ot0, 0, 0, 0);\
    ot1 = __builtin_amdgcn_mfma_f32_32x32x16_bf16(                            \
        *(const bf16x8*)(&Vs[SL][32 + lo][(hi * 8) ^ sw2]), F0_, ot1, 0, 0, 0);\
    ot1 = __builtin_amdgcn_mfma_f32_32x32x16_bf16(                            \
        *(const bf16x8*)(&Vs[SL][32 + lo][(16 + hi * 8) ^ sw2]), F1_, ot1, 0, 0, 0);\
    __builtin_amdgcn_s_setprio(0);                                            \
  }

// one pipeline step; vmcnt(3): retire set at step t is exactly {V_t, K_{t+1}}
// (what FIN(t)/QK(t+1) need next step) -> 3 loads stay in flight across barrier
#define STEP(T, SACUR, SAPRV, QSL, FSL, SSL)                                  \
  {                                                                           \
    STAGE((T) + 2, SSL);                                                      \
    QK(QSL, SACUR);                                                           \
    FIN(SAPRV, FSL);                                                          \
    asm volatile("s_waitcnt vmcnt(3)" ::: "memory");                          \
    __builtin_amdgcn_s_barrier();                                             \
  }

__global__ __launch_bounds__(256) void attn_kernel(AttnArgs aa) {
  __shared__ alignas(16) bf16_t Ks[4][32][64];   // 16KB, 3-bit XOR swizzle
  __shared__ alignas(16) bf16_t Vs[4][64][32];   // 8KB,  V^T, 2-bit XOR swizzle
  // XCD-aware decode: all 13 q-tiles of one (s,b,h) on one XCD
  int id = blockIdx.x;
  int xcd = id & 7, sl = id >> 3;          // sl in 0..103
  int g = xcd + ((sl / 13) << 3);          // group 0..63
  int qt = sl % 13;
  int ss = g >> 5, b = (g >> 3) & 3, h = g & 7;
  const bf16_t* qg = aa.q[ss];
  const bf16_t* kgp = aa.k[ss];
  const bf16_t* vtg = aa.v[ss];
  float* tf = aa.tf[ss];
  bf16_t* tb = aa.tb[ss];
  int tid = threadIdx.x, w = tid >> 6, l = tid & 63;
  int lo = l & 31, hi = l >> 5;
  int wq8 = w * 8, wq16 = w * 16;
  int sw3 = (lo & 7) << 3;
  int sw2 = ((lo >> 1) & 3) << 3;
  const size_t kbase = ((size_t)b * NTOK) * CDIM + h * 64;
  const size_t vbase = ((size_t)b * CDIM + h * 64) * NTOK;

  int q0 = qt * 128 + w * 32;
  int qrow = q0 + lo;
  int qr = qrow < NTOK ? qrow : NTOK - 1;
  const bf16_t* qp = qg + kbase + (size_t)qr * CDIM + hi * 8;
  bf16x8 qf[4];
  qf[0] = *(const bf16x8*)(qp);
  qf[1] = *(const bf16x8*)(qp + 16);
  qf[2] = *(const bf16x8*)(qp + 32);
  qf[3] = *(const bf16x8*)(qp + 48);
  asm volatile("" : "+v"(qf[0]), "+v"(qf[1]), "+v"(qf[2]), "+v"(qf[3]));
  asm volatile("s_waitcnt vmcnt(0)" ::: "memory");   // drain Q so vmcnt counting is exact

  // staging source addresses (pre-swizzled col-groups; store perm matches read perm)
  const bf16_t* kgl = kgp + kbase + (size_t)(wq8 + (l >> 3)) * CDIM
                      + (((l & 7) ^ ((l >> 3) & 7)) << 3);
  const bf16_t* vgl = vtg + vbase + (size_t)(wq16 + (l >> 2)) * NTOK
                      + (((l & 3) ^ ((l >> 3) & 3)) << 3);

  // ones fragment for the denominator MFMA
  bf16x8 kone;
#pragma unroll
  for (int j = 0; j < 8; j++) kone[j] = (bf16_t)1.0f;

  f32x16 ot0, ot1, ls, z, saA, saB;
#pragma unroll
  for (int r = 0; r < 16; r++) { ot0[r] = 0.f; ot1[r] = 0.f; ls[r] = 0.f; z[r] = 0.f; }

  // prologue: stage tiles 0,1,2; retire 0,1; compute QK(0)
  STAGE(0, 0);
  STAGE(1, 1);
  STAGE(2, 2);
  asm volatile("s_waitcnt vmcnt(2)" ::: "memory");
  __builtin_amdgcn_s_barrier();
  QK(0, saA);

  // steady loop: steps t=1..48 (12 x 4, residues fixed)
  for (int t = 1; t <= 45; t += 4) {
    STEP(t + 0, saB, saA, 1, 0, 3);
    STEP(t + 1, saA, saB, 2, 1, 0);
    STEP(t + 2, saB, saA, 3, 2, 1);
    STEP(t + 3, saA, saB, 0, 3, 2);
  }
  // finish tile 48 (slot 0)
  FIN(saA, 0);

  if (qrow < NTOK) {
    float inv = 1.f / ls[0];     // all ls rows identical; lane's col = its q
    float* tfp = tf + ((size_t)b * NTOK + qrow) * CDIM + h * 64 + hi * 4;
    bf16_t* tbp = tb + ((size_t)b * NTOK + qrow) * CDIM + h * 64 + hi * 4;
#pragma unroll
    for (int db = 0; db < 2; db++) {
#pragma unroll
      for (int gq = 0; gq < 4; gq++) {
        int doff = db * 32 + gq * 8;
        float4 old = *(float4*)(tfp + doff);
        float4 nv;
        float a0 = (db ? ot1[gq * 4 + 0] : ot0[gq * 4 + 0]) * inv;
        float a1 = (db ? ot1[gq * 4 + 1] : ot0[gq * 4 + 1]) * inv;
        float a2 = (db ? ot1[gq * 4 + 2] : ot0[gq * 4 + 2]) * inv;
        float a3 = (db ? ot1[gq * 4 + 3] : ot0[gq * 4 + 3]) * inv;
        nv.x = old.x + a0; nv.y = old.y + a1; nv.z = old.z + a2; nv.w = old.w + a3;
        *(float4*)(tfp + doff) = nv;
        bf16x4 ob;
        ob[0] = (bf16_t)nv.x; ob[1] = (bf16_t)nv.y;
        ob[2] = (bf16_t)nv.z; ob[3] = (bf16_t)nv.w;
        *(bf16x4*)(tbp + doff) = ob;
      }
    }
  }
}

extern "C" void kernel_launch(void* const* d_in, const int* in_sizes, int n_in,
                              void* d_out, int out_size, void* d_ws, size_t ws_size,
                              hipStream_t stream) {
  (void)in_sizes; (void)n_in; (void)out_size; (void)ws_size;
  const float* x1 = (const float*)d_in[0];
  const float* x2 = (const float*)d_in[1];
  const float* Wq1 = (const float*)d_in[2];
  const float* bq1 = (const float*)d_in[3];
  const float* Wk1 = (const float*)d_in[4];
  const float* bk1 = (const float*)d_in[5];
  const float* Wv1 = (const float*)d_in[6];
  const float* bv1 = (const float*)d_in[7];
  const float* ln1_g = (const float*)d_in[8];
  const float* ln1_b = (const float*)d_in[9];
  const float* Wq2 = (const float*)d_in[10];
  const float* bq2 = (const float*)d_in[11];
  const float* Wk2 = (const float*)d_in[12];
  const float* bk2 = (const float*)d_in[13];
  const float* Wv2 = (const float*)d_in[14];
  const float* bv2 = (const float*)d_in[15];
  const float* ln2_g = (const float*)d_in[16];
  const float* ln2_b = (const float*)d_in[17];
  const float* out1_w = (const float*)d_in[18];
  const float* out1_b = (const float*)d_in[19];
  const float* bn1_g = (const float*)d_in[20];
  const float* bn1_b = (const float*)d_in[21];
  const float* out2_w = (const float*)d_in[22];
  const float* out2_b = (const float*)d_in[23];
  const float* bn2_g = (const float*)d_in[24];
  const float* bn2_b = (const float*)d_in[25];

  const size_t WMAT = 512 * 512;
  char* ws = (char*)d_ws;
  bf16_t* wb = (bf16_t*)ws;
  size_t off = 20 * WMAT * sizeof(bf16_t);
  float* t1f = (float*)(ws + off); off += (size_t)MROWS * CDIM * 4;
  float* t2f = (float*)(ws + off); off += (size_t)MROWS * CDIM * 4;
  bf16_t* t1b = (bf16_t*)(ws + off); off += (size_t)MROWS * CDIM * 2;
  bf16_t* t2b = (bf16_t*)(ws + off); off += (size_t)MROWS * CDIM * 2;
  bf16_t* l1b = (bf16_t*)(ws + off); off += (size_t)MROWS * CDIM * 2;
  bf16_t* l2b = (bf16_t*)(ws + off); off += (size_t)MROWS * CDIM * 2;
  bf16_t* q1b = (bf16_t*)(ws + off); off += (size_t)MROWS * CDIM * 2;
  bf16_t* k1b = (bf16_t*)(ws + off); off += (size_t)MROWS * CDIM * 2;
  bf16_t* v1b = (bf16_t*)(ws + off); off += (size_t)MROWS * CDIM * 2;  // V^T [b][512][1568]
  bf16_t* q2b = (bf16_t*)(ws + off); off += (size_t)MROWS * CDIM * 2;
  bf16_t* k2b = (bf16_t*)(ws + off); off += (size_t)MROWS * CDIM * 2;
  bf16_t* v2b = (bf16_t*)(ws + off); off += (size_t)MROWS * CDIM * 2;  // V^T

  CastArgs ca;
  for (int i = 0; i < 3; i++) {
    ca.s[0 + i] = Wq1 + (size_t)i * WMAT;
    ca.s[3 + i] = Wk1 + (size_t)i * WMAT;
    ca.s[6 + i] = Wv1 + (size_t)i * WMAT;
    ca.s[9 + i] = Wq2 + (size_t)i * WMAT;
    ca.s[12 + i] = Wk2 + (size_t)i * WMAT;
    ca.s[15 + i] = Wv2 + (size_t)i * WMAT;
  }
  ca.s[18] = out1_w;
  ca.s[19] = out2_w;
  cast_kernel<<<5120, 256, 0, stream>>>(ca, wb);

  TokArgs ta;
  ta.x[0] = x1; ta.x[1] = x2;
  ta.tf[0] = t1f; ta.tf[1] = t2f;
  ta.tb[0] = t1b; ta.tb[1] = t2b;
  tok_kernel<<<dim3(49, 16, 8), dim3(32, 8), 0, stream>>>(ta);

  AttnArgs aa;
  aa.q[0] = q1b; aa.q[1] = q2b;
  aa.k[0] = k1b; aa.k[1] = k2b;
  aa.v[0] = v1b; aa.v[1] = v2b;
  aa.tf[0] = t1f; aa.tf[1] = t2f;
  aa.tb[0] = t1b; aa.tb[1] = t2b;

  for (int i = 0; i < 3; i++) {
    ln_kernel<<<2 * MROWS, 64, 0, stream>>>(t1f, t2f,
        ln1_g + i * 512, ln1_b + i * 512, ln2_g + i * 512, ln2_b + i * 512,
        l1b, l2b);
    ProjArgs pa;
    pa.A0[0] = l1b; pa.W0[0] = wb + (0 + i) * WMAT; pa.b0[0] = bq1 + i * 512; pa.o0[0] = q1b;
    pa.A0[1] = t2b; pa.W0[1] = wb + (3 + i) * WMAT; pa.b0[1] = bk1 + i * 512; pa.o0[1] = k1b;
    pa.A0[2] = l2b; pa.W0[2] = wb + (9 + i) * WMAT; pa.b0[2] = bq2 + i * 512; pa.o0[2] = q2b;
    pa.A0[3] = t1b; pa.W0[3] = wb + (12 + i) * WMAT; pa.b0[3] = bk2 + i * 512; pa.o0[3] = k2b;
    pa.scl0[0] = CEXP; pa.scl0[1] = 1.f; pa.scl0[2] = CEXP; pa.scl0[3] = 1.f;
    pa.W2[0] = wb + (6 + i) * WMAT; pa.B2[0] = t2b; pa.b2[0] = bv1 + i * 512; pa.o2[0] = v1b;
    pa.W2[1] = wb + (15 + i) * WMAT; pa.B2[1] = t1b; pa.b2[1] = bv2 + i * 512; pa.o2[1] = v2b;
    proj_kernel<<<1200, 256, 0, stream>>>(pa);
    attn_kernel<<<832, 256, 0, stream>>>(aa);
  }

  float* out = (float*)d_out;
  head_kernel<<<dim3(13, 4, 8), 256, 0, stream>>>(
      wb + 18 * WMAT, wb + 19 * WMAT, t1b, t2b,
      out1_b, out2_b, bn1_g, bn1_b, bn2_g, bn2_b, out);
}

// Round 15
// 394.031 us; speedup vs baseline: 1.1855x; 1.0101x over previous
//
#include <hip/hip_runtime.h>

typedef __bf16 bf16_t;
typedef __bf16 bf16x8 __attribute__((ext_vector_type(8)));
typedef __bf16 bf16x4 __attribute__((ext_vector_type(4)));
typedef float f32x4 __attribute__((ext_vector_type(4)));
typedef float f32x16 __attribute__((ext_vector_type(16)));
typedef unsigned u32x4 __attribute__((ext_vector_type(4)));

#define NTOK 1568
#define CDIM 512
#define BATCH 4
#define MROWS (BATCH*NTOK)  // 6272
#define RSQ1PEPS 0.9999950000374997f
#define CEXP 0.1803368801111204f    // 0.125 * log2(e), folded into q-projection

__device__ __forceinline__ float fexp2(float x) {
  float r;
  asm("v_exp_f32 %0, %1" : "=v"(r) : "v"(x));
  return r;
}

__device__ __forceinline__ void glds16(const bf16_t* src, bf16_t* dst) {
  __builtin_amdgcn_global_load_lds(
      (const __attribute__((address_space(1))) unsigned*)src,
      (__attribute__((address_space(3))) unsigned*)dst, 16, 0, 0);
}

// ---------------- cast all weights f32 -> bf16 (one launch) ----------------
struct CastArgs { const float* s[20]; };
__global__ __launch_bounds__(256) void cast_kernel(CastArgs ca, bf16_t* __restrict__ out) {
  int idx = blockIdx.x * 256 + threadIdx.x;
  int m = idx >> 16;
  const float4* sp = (const float4*)ca.s[m];
  float4 v = sp[idx & 65535];
  bf16x4 o;
  o[0] = (bf16_t)v.x; o[1] = (bf16_t)v.y; o[2] = (bf16_t)v.z; o[3] = (bf16_t)v.w;
  *(bf16x4*)(out + (size_t)idx * 4) = o;
}

// ---------------- tokenize both inputs: x[b][c][s] -> t[b][s][c] ----------------
struct TokArgs { const float* x[2]; float* tf[2]; bf16_t* tb[2]; };
__global__ __launch_bounds__(256) void tok_kernel(TokArgs ta) {
  __shared__ float tile[32][33];
  int z = blockIdx.z, sel = z >> 2, b = z & 3;
  int c0 = blockIdx.y * 32, s0 = blockIdx.x * 32;
  int tx = threadIdx.x, ty = threadIdx.y;
  const float* xp = ta.x[sel] + (size_t)b * CDIM * NTOK;
  for (int r = 0; r < 32; r += 8)
    tile[ty + r][tx] = xp[(size_t)(c0 + ty + r) * NTOK + s0 + tx];
  __syncthreads();
  float* tfp = ta.tf[sel] + (size_t)b * NTOK * CDIM;
  bf16_t* tbp = ta.tb[sel] + (size_t)b * NTOK * CDIM;
  for (int r = 0; r < 32; r += 8) {
    float v = tile[tx][ty + r];
    size_t idx = (size_t)(s0 + ty + r) * CDIM + c0 + tx;
    tfp[idx] = v;
    tbp[idx] = (bf16_t)v;
  }
}

// ---------------- LayerNorm both streams: f32 in -> bf16 out ----------------
__global__ __launch_bounds__(64) void ln_kernel(
    const float* __restrict__ t1, const float* __restrict__ t2,
    const float* __restrict__ g1, const float* __restrict__ b1,
    const float* __restrict__ g2, const float* __restrict__ b2,
    bf16_t* __restrict__ o1, bf16_t* __restrict__ o2) {
  int row = blockIdx.x;
  const float* t; const float* g; const float* bt; bf16_t* out;
  if (row < MROWS) { t = t1; g = g1; bt = b1; out = o1; }
  else { row -= MROWS; t = t2; g = g2; bt = b2; out = o2; }
  int l = threadIdx.x;
  const float* x = t + (size_t)row * CDIM;
  float4 v0 = ((const float4*)x)[l];
  float4 v1 = ((const float4*)x)[l + 64];
  float s = v0.x + v0.y + v0.z + v0.w + v1.x + v1.y + v1.z + v1.w;
  float sq = v0.x*v0.x + v0.y*v0.y + v0.z*v0.z + v0.w*v0.w
           + v1.x*v1.x + v1.y*v1.y + v1.z*v1.z + v1.w*v1.w;
  for (int m = 1; m < 64; m <<= 1) { s += __shfl_xor(s, m); sq += __shfl_xor(sq, m); }
  float mean = s * (1.f / 512.f);
  float var = sq * (1.f / 512.f) - mean * mean;
  float rs = rsqrtf(var + 1e-5f);
  float4 g0 = ((const float4*)g)[l], g1v = ((const float4*)g)[l + 64];
  float4 b0 = ((const float4*)bt)[l], b1v = ((const float4*)bt)[l + 64];
  bf16x4 o0, o1v;
  o0[0] = (bf16_t)((v0.x - mean) * rs * g0.x + b0.x);
  o0[1] = (bf16_t)((v0.y - mean) * rs * g0.y + b0.y);
  o0[2] = (bf16_t)((v0.z - mean) * rs * g0.z + b0.z);
  o0[3] = (bf16_t)((v0.w - mean) * rs * g0.w + b0.w);
  o1v[0] = (bf16_t)((v1.x - mean) * rs * g1v.x + b1v.x);
  o1v[1] = (bf16_t)((v1.y - mean) * rs * g1v.y + b1v.y);
  o1v[2] = (bf16_t)((v1.z - mean) * rs * g1v.z + b1v.z);
  o1v[3] = (bf16_t)((v1.w - mean) * rs * g1v.w + b1v.w);
  *(bf16x4*)(out + (size_t)row * CDIM + l * 4) = o0;
  *(bf16x4*)(out + (size_t)row * CDIM + 256 + l * 4) = o1v;
}

// ---------------- shared GEMM core: D = A[M][512] * B[N][512]^T ----------------
template<int MODE>
__device__ __forceinline__ void gemm_core(
    bf16_t (* __restrict__ As)[40], bf16_t (* __restrict__ Bs)[40],
    const bf16_t* __restrict__ A, const bf16_t* __restrict__ Bp,
    const float* __restrict__ bias, const float* __restrict__ bng,
    const float* __restrict__ bnb, bf16_t* __restrict__ outb,
    float* __restrict__ outf, int m0, int n0, int Nvalid, float scl) {
  int tid = threadIdx.x;
  int w = tid >> 6, l = tid & 63, lr = l & 15, kg = l >> 4;
  int wm = (w >> 1) * 64, wn = (w & 1) * 64;
  f32x4 acc[4][4];
  for (int i = 0; i < 4; i++)
    for (int j = 0; j < 4; j++)
      acc[i][j] = f32x4{0.f, 0.f, 0.f, 0.f};
  int srow = tid >> 1;
  int soff = (tid & 1) * 16;
  int brow = n0 + srow;
  if (MODE != 0 && brow >= Nvalid) brow = Nvalid - 1;
  const bf16_t* aq = A + (size_t)(m0 + srow) * CDIM + soff;
  const bf16_t* bq = Bp + (size_t)brow * CDIM + soff;
  for (int kk = 0; kk < 16; kk++) {
    __syncthreads();
    bf16x8 a0 = *(const bf16x8*)(aq);
    bf16x8 a1 = *(const bf16x8*)(aq + 8);
    bf16x8 b0 = *(const bf16x8*)(bq);
    bf16x8 b1 = *(const bf16x8*)(bq + 8);
    aq += 32; bq += 32;
    *(bf16x8*)&As[srow][soff] = a0;
    *(bf16x8*)&As[srow][soff + 8] = a1;
    *(bf16x8*)&Bs[srow][soff] = b0;
    *(bf16x8*)&Bs[srow][soff + 8] = b1;
    __syncthreads();
    bf16x8 af[4], bfr[4];
    for (int i = 0; i < 4; i++) af[i] = *(const bf16x8*)&As[wm + i * 16 + lr][kg * 8];
    for (int j = 0; j < 4; j++) bfr[j] = *(const bf16x8*)&Bs[wn + j * 16 + lr][kg * 8];
    for (int i = 0; i < 4; i++)
      for (int j = 0; j < 4; j++)
        acc[i][j] = __builtin_amdgcn_mfma_f32_16x16x32_bf16(af[i], bfr[j], acc[i][j], 0, 0, 0);
  }
  for (int i = 0; i < 4; i++)
    for (int j = 0; j < 4; j++) {
      int rbase = m0 + wm + i * 16 + kg * 4;
      int col = n0 + wn + j * 16 + lr;
      for (int r = 0; r < 4; r++) {
        int row = rbase + r;
        float v = acc[i][j][r];
        if (MODE == 0) {
          v = (v + bias[col]) * scl;
          outb[(size_t)row * CDIM + col] = (bf16_t)v;
        } else if (MODE == 1) {
          v += bias[row];
          v = v > 0.f ? v : 0.f;
          v *= RSQ1PEPS;
          v = v * bng[row] + bnb[row];
          if (col < Nvalid) outf[(size_t)row * NTOK + col] = v;
        } else {
          v += bias[row];
          if (col < Nvalid) outb[(size_t)row * NTOK + col] = (bf16_t)v;
        }
      }
    }
}

// ---------------- fused per-stage projections ----------------
struct ProjArgs {
  const bf16_t* A0[4]; const bf16_t* W0[4]; const float* b0[4]; bf16_t* o0[4];
  float scl0[4];
  const bf16_t* W2[2]; const bf16_t* B2[2]; const float* b2[2]; bf16_t* o2[2];
};
__global__ __launch_bounds__(256) void proj_kernel(ProjArgs p) {
  __shared__ bf16_t As[128][40];
  __shared__ bf16_t Bs[128][40];
  int id = blockIdx.x;
  if (id < 784) {
    int set = id / 196, rem = id % 196;
    int n0 = (rem & 3) * 128, m0 = (rem >> 2) * 128;
    gemm_core<0>(As, Bs, p.A0[set], p.W0[set], p.b0[set], nullptr, nullptr,
                 p.o0[set], nullptr, m0, n0, 512, p.scl0[set]);
  } else {
    int j = id - 784;
    int unit = j / 52;
    int which = unit >> 2, bat = unit & 3;
    int rem = j % 52;
    int n0 = (rem % 13) * 128, m0 = (rem / 13) * 128;
    gemm_core<2>(As, Bs, p.W2[which], p.B2[which] + (size_t)bat * NTOK * CDIM,
                 p.b2[which], nullptr, nullptr,
                 p.o2[which] + (size_t)bat * CDIM * NTOK, nullptr, m0, n0, NTOK, 1.f);
  }
}

// ---------------- fused out-heads (MODE 1) ----------------
__global__ __launch_bounds__(256) void head_kernel(
    const bf16_t* __restrict__ W1, const bf16_t* __restrict__ W2,
    const bf16_t* __restrict__ t1b, const bf16_t* __restrict__ t2b,
    const float* __restrict__ b1, const float* __restrict__ b2,
    const float* __restrict__ bng1, const float* __restrict__ bnb1,
    const float* __restrict__ bng2, const float* __restrict__ bnb2,
    float* __restrict__ out) {
  __shared__ bf16_t As[128][40];
  __shared__ bf16_t Bs[128][40];
  int z = blockIdx.z;
  int which = z >> 2, bat = z & 3;
  const bf16_t* A = which ? W2 : W1;
  const bf16_t* Bp = (which ? t2b : t1b) + (size_t)bat * NTOK * CDIM;
  const float* bias = which ? b2 : b1;
  const float* bng = which ? bng2 : bng1;
  const float* bnb = which ? bnb2 : bnb1;
  float* outf = out + (size_t)which * BATCH * CDIM * NTOK + (size_t)bat * CDIM * NTOK;
  int m0 = blockIdx.y * 128, n0 = blockIdx.x * 128;
  gemm_core<1>(As, Bs, A, Bp, bias, bng, bnb, nullptr, outf, m0, n0, NTOK, 1.f);
}

// ---------------- attention helpers ----------------
__device__ __forceinline__ void build_frags(const float* p, bf16x8& Fa, bf16x8& Fb) {
  unsigned pk[8];
#pragma unroll
  for (int g = 0; g < 8; g++) {
    union { bf16_t hh[2]; unsigned u; } cv;
    cv.hh[0] = (bf16_t)p[2 * g];
    cv.hh[1] = (bf16_t)p[2 * g + 1];
    pk[g] = cv.u;
  }
  asm volatile("v_permlane32_swap_b32 %0, %1" : "+v"(pk[0]), "+v"(pk[2]));
  asm volatile("v_permlane32_swap_b32 %0, %1" : "+v"(pk[1]), "+v"(pk[3]));
  asm volatile("v_permlane32_swap_b32 %0, %1" : "+v"(pk[4]), "+v"(pk[6]));
  asm volatile("v_permlane32_swap_b32 %0, %1" : "+v"(pk[5]), "+v"(pk[7]));
  union { u32x4 u; bf16x8 bv; } A, B;
  A.u[0] = pk[0]; A.u[1] = pk[1]; A.u[2] = pk[2]; A.u[3] = pk[3];
  B.u[0] = pk[4]; B.u[1] = pk[5]; B.u[2] = pk[6]; B.u[3] = pk[7];
  Fa = A.bv; Fb = B.bv;
}

// ---------------- fused attention: KVB=32, ring-5 depth-3, T15, static-max ----------------
struct AttnArgs {
  const bf16_t* q[2]; const bf16_t* k[2]; const bf16_t* v[2];
  float* tf[2]; bf16_t* tb[2];
};

#define STAGE(TN, SL)                                                         \
  {                                                                           \
    int tnS_ = (TN); if (tnS_ > 48) tnS_ = 48;                                \
    glds16(kgl + (size_t)tnS_ * (32 * CDIM), &Ks[SL][wq8][0]);                \
    glds16(vgl + tnS_ * 32, &Vs[SL][wq16][0]);                                \
  }

#define QK(SL, SA)                                                            \
  {                                                                           \
    const bf16_t* kr_ = &Ks[SL][lo][0];                                       \
    __builtin_amdgcn_s_setprio(1);                                            \
    SA = __builtin_amdgcn_mfma_f32_32x32x16_bf16(                             \
        *(const bf16x8*)(kr_ + ((hi * 8) ^ sw3)), qf[0], z, 0, 0, 0);         \
    SA = __builtin_amdgcn_mfma_f32_32x32x16_bf16(                             \
        *(const bf16x8*)(kr_ + ((16 + hi * 8) ^ sw3)), qf[1], SA, 0, 0, 0);   \
    SA = __builtin_amdgcn_mfma_f32_32x32x16_bf16(                             \
        *(const bf16x8*)(kr_ + ((32 + hi * 8) ^ sw3)), qf[2], SA, 0, 0, 0);   \
    SA = __builtin_amdgcn_mfma_f32_32x32x16_bf16(                             \
        *(const bf16x8*)(kr_ + ((48 + hi * 8) ^ sw3)), qf[3], SA, 0, 0, 0);   \
    __builtin_amdgcn_s_setprio(0);                                            \
  }

#define FIN(SA, SL)                                                           \
  {                                                                           \
    float pa_[16];                                                            \
    _Pragma("unroll")                                                         \
    for (int r_ = 0; r_ < 16; r_++) pa_[r_] = fexp2(SA[r_]);                  \
    bf16x8 F0_, F1_;                                                          \
    build_frags(pa_, F0_, F1_);                                               \
    __builtin_amdgcn_s_setprio(1);                                            \
    ls = __builtin_amdgcn_mfma_f32_32x32x16_bf16(kone, F0_, ls, 0, 0, 0);     \
    ls = __builtin_amdgcn_mfma_f32_32x32x16_bf16(kone, F1_, ls, 0, 0, 0);     \
    ot0 = __builtin_amdgcn_mfma_f32_32x32x16_bf16(                            \
        *(const bf16x8*)(&Vs[SL][lo][(hi * 8) ^ sw2]), F0_, ot0, 0, 0, 0);    \
    ot0 = __builtin_amdgcn_mfma_f32_32x32x16_bf16(                            \
        *(const bf16x8*)(&Vs[SL][lo][(16 + hi * 8) ^ sw2]), F1_, ot0, 0, 0, 0);\
    ot1 = __builtin_amdgcn_mfma_f32_32x32x16_bf16(                            \
        *(const bf16x8*)(&Vs[SL][32 + lo][(hi * 8) ^ sw2]), F0_, ot1, 0, 0, 0);\
    ot1 = __builtin_amdgcn_mfma_f32_32x32x16_bf16(                            \
        *(const bf16x8*)(&Vs[SL][32 + lo][(16 + hi * 8) ^ sw2]), F1_, ot1, 0, 0, 0);\
    __builtin_amdgcn_s_setprio(0);                                            \
  }

// one step; depth-3 prefetch (stage t+3), vmcnt(4) keeps 2 tiles in flight:
// the barrier retires exactly the tile needed NEXT step, never fresh loads.
#define STEP1(T, SACUR, SAPRV, QSL, FSL, SSL)                                 \
  {                                                                           \
    STAGE((T) + 3, SSL);                                                      \
    QK(QSL, SACUR);                                                           \
    FIN(SAPRV, FSL);                                                          \
    asm volatile("s_waitcnt vmcnt(4)" ::: "memory");                          \
    __builtin_amdgcn_s_barrier();                                             \
  }

__global__ __launch_bounds__(256) void attn_kernel(AttnArgs aa) {
  __shared__ alignas(16) bf16_t Ks[5][32][64];   // 20KB, 3-bit XOR swizzle
  __shared__ alignas(16) bf16_t Vs[5][64][32];   // 20KB, V^T, 2-bit XOR swizzle
  // XCD-aware decode: all 13 q-tiles of one (s,b,h) on one XCD
  int id = blockIdx.x;
  int xcd = id & 7, sl = id >> 3;          // sl in 0..103
  int g = xcd + ((sl / 13) << 3);          // group 0..63
  int qt = sl % 13;
  int ss = g >> 5, b = (g >> 3) & 3, h = g & 7;
  const bf16_t* qg = aa.q[ss];
  const bf16_t* kgp = aa.k[ss];
  const bf16_t* vtg = aa.v[ss];
  float* tf = aa.tf[ss];
  bf16_t* tb = aa.tb[ss];
  int tid = threadIdx.x, w = tid >> 6, l = tid & 63;
  int lo = l & 31, hi = l >> 5;
  int wq8 = w * 8, wq16 = w * 16;
  int sw3 = (lo & 7) << 3;
  int sw2 = ((lo >> 1) & 3) << 3;
  const size_t kbase = ((size_t)b * NTOK) * CDIM + h * 64;
  const size_t vbase = ((size_t)b * CDIM + h * 64) * NTOK;

  int q0 = qt * 128 + w * 32;
  int qrow = q0 + lo;
  int qr = qrow < NTOK ? qrow : NTOK - 1;
  const bf16_t* qp = qg + kbase + (size_t)qr * CDIM + hi * 8;
  bf16x8 qf[4];
  qf[0] = *(const bf16x8*)(qp);
  qf[1] = *(const bf16x8*)(qp + 16);
  qf[2] = *(const bf16x8*)(qp + 32);
  qf[3] = *(const bf16x8*)(qp + 48);
  asm volatile("" : "+v"(qf[0]), "+v"(qf[1]), "+v"(qf[2]), "+v"(qf[3]));
  asm volatile("s_waitcnt vmcnt(0)" ::: "memory");   // drain Q so vmcnt counting is exact

  // staging source addresses (pre-swizzled col-groups; store perm matches read perm)
  const bf16_t* kgl = kgp + kbase + (size_t)(wq8 + (l >> 3)) * CDIM
                      + (((l & 7) ^ ((l >> 3) & 7)) << 3);
  const bf16_t* vgl = vtg + vbase + (size_t)(wq16 + (l >> 2)) * NTOK
                      + (((l & 3) ^ ((l >> 3) & 3)) << 3);

  // ones fragment for the denominator MFMA
  bf16x8 kone;
#pragma unroll
  for (int j = 0; j < 8; j++) kone[j] = (bf16_t)1.0f;

  f32x16 ot0, ot1, ls, z, saA, saB;
#pragma unroll
  for (int r = 0; r < 16; r++) { ot0[r] = 0.f; ot1[r] = 0.f; ls[r] = 0.f; z[r] = 0.f; }

  // prologue: stage tiles 0..3; retire 0,1; compute QK(0)
  STAGE(0, 0);
  STAGE(1, 1);
  STAGE(2, 2);
  STAGE(3, 3);
  asm volatile("s_waitcnt vmcnt(4)" ::: "memory");
  __builtin_amdgcn_s_barrier();
  QK(0, saA);

  // steady loop: steps 1..40 (4 x 10, slot period 5 x sa period 2)
  for (int t = 1; t <= 31; t += 10) {
    STEP1(t + 0, saB, saA, 1, 0, 4);
    STEP1(t + 1, saA, saB, 2, 1, 0);
    STEP1(t + 2, saB, saA, 3, 2, 1);
    STEP1(t + 3, saA, saB, 4, 3, 2);
    STEP1(t + 4, saB, saA, 0, 4, 3);
    STEP1(t + 5, saA, saB, 1, 0, 4);
    STEP1(t + 6, saB, saA, 2, 1, 0);
    STEP1(t + 7, saA, saB, 3, 2, 1);
    STEP1(t + 8, saB, saA, 4, 3, 2);
    STEP1(t + 9, saA, saB, 0, 4, 3);
  }
  // tail steps 41..48
  STEP1(41, saB, saA, 1, 0, 4);
  STEP1(42, saA, saB, 2, 1, 0);
  STEP1(43, saB, saA, 3, 2, 1);
  STEP1(44, saA, saB, 4, 3, 2);
  STEP1(45, saB, saA, 0, 4, 3);
  STEP1(46, saA, saB, 1, 0, 4);
  STEP1(47, saB, saA, 2, 1, 0);
  STEP1(48, saA, saB, 3, 2, 1);
  // finish tile 48 (slot 48%5 = 3)
  FIN(saA, 3);
  asm volatile("s_waitcnt vmcnt(0)" ::: "memory");   // drain clamped dup stages

  if (qrow < NTOK) {
    float inv = 1.f / ls[0];     // all ls rows identical; lane's col = its q
    float* tfp = tf + ((size_t)b * NTOK + qrow) * CDIM + h * 64 + hi * 4;
    bf16_t* tbp = tb + ((size_t)b * NTOK + qrow) * CDIM + h * 64 + hi * 4;
#pragma unroll
    for (int db = 0; db < 2; db++) {
#pragma unroll
      for (int gq = 0; gq < 4; gq++) {
        int doff = db * 32 + gq * 8;
        float4 old = *(float4*)(tfp + doff);
        float4 nv;
        float a0 = (db ? ot1[gq * 4 + 0] : ot0[gq * 4 + 0]) * inv;
        float a1 = (db ? ot1[gq * 4 + 1] : ot0[gq * 4 + 1]) * inv;
        float a2 = (db ? ot1[gq * 4 + 2] : ot0[gq * 4 + 2]) * inv;
        float a3 = (db ? ot1[gq * 4 + 3] : ot0[gq * 4 + 3]) * inv;
        nv.x = old.x + a0; nv.y = old.y + a1; nv.z = old.z + a2; nv.w = old.w + a3;
        *(float4*)(tfp + doff) = nv;
        bf16x4 ob;
        ob[0] = (bf16_t)nv.x; ob[1] = (bf16_t)nv.y;
        ob[2] = (bf16_t)nv.z; ob[3] = (bf16_t)nv.w;
        *(bf16x4*)(tbp + doff) = ob;
      }
    }
  }
}

extern "C" void kernel_launch(void* const* d_in, const int* in_sizes, int n_in,
                              void* d_out, int out_size, void* d_ws, size_t ws_size,
                              hipStream_t stream) {
  (void)in_sizes; (void)n_in; (void)out_size; (void)ws_size;
  const float* x1 = (const float*)d_in[0];
  const float* x2 = (const float*)d_in[1];
  const float* Wq1 = (const float*)d_in[2];
  const float* bq1 = (const float*)d_in[3];
  const float* Wk1 = (const float*)d_in[4];
  const float* bk1 = (const float*)d_in[5];
  const float* Wv1 = (const float*)d_in[6];
  const float* bv1 = (const float*)d_in[7];
  const float* ln1_g = (const float*)d_in[8];
  const float* ln1_b = (const float*)d_in[9];
  const float* Wq2 = (const float*)d_in[10];
  const float* bq2 = (const float*)d_in[11];
  const float* Wk2 = (const float*)d_in[12];
  const float* bk2 = (const float*)d_in[13];
  const float* Wv2 = (const float*)d_in[14];
  const float* bv2 = (const float*)d_in[15];
  const float* ln2_g = (const float*)d_in[16];
  const float* ln2_b = (const float*)d_in[17];
  const float* out1_w = (const float*)d_in[18];
  const float* out1_b = (const float*)d_in[19];
  const float* bn1_g = (const float*)d_in[20];
  const float* bn1_b = (const float*)d_in[21];
  const float* out2_w = (const float*)d_in[22];
  const float* out2_b = (const float*)d_in[23];
  const float* bn2_g = (const float*)d_in[24];
  const float* bn2_b = (const float*)d_in[25];

  const size_t WMAT = 512 * 512;
  char* ws = (char*)d_ws;
  bf16_t* wb = (bf16_t*)ws;
  size_t off = 20 * WMAT * sizeof(bf16_t);
  float* t1f = (float*)(ws + off); off += (size_t)MROWS * CDIM * 4;
  float* t2f = (float*)(ws + off); off += (size_t)MROWS * CDIM * 4;
  bf16_t* t1b = (bf16_t*)(ws + off); off += (size_t)MROWS * CDIM * 2;
  bf16_t* t2b = (bf16_t*)(ws + off); off += (size_t)MROWS * CDIM * 2;
  bf16_t* l1b = (bf16_t*)(ws + off); off += (size_t)MROWS * CDIM * 2;
  bf16_t* l2b = (bf16_t*)(ws + off); off += (size_t)MROWS * CDIM * 2;
  bf16_t* q1b = (bf16_t*)(ws + off); off += (size_t)MROWS * CDIM * 2;
  bf16_t* k1b = (bf16_t*)(ws + off); off += (size_t)MROWS * CDIM * 2;
  bf16_t* v1b = (bf16_t*)(ws + off); off += (size_t)MROWS * CDIM * 2;  // V^T [b][512][1568]
  bf16_t* q2b = (bf16_t*)(ws + off); off += (size_t)MROWS * CDIM * 2;
  bf16_t* k2b = (bf16_t*)(ws + off); off += (size_t)MROWS * CDIM * 2;
  bf16_t* v2b = (bf16_t*)(ws + off); off += (size_t)MROWS * CDIM * 2;  // V^T

  CastArgs ca;
  for (int i = 0; i < 3; i++) {
    ca.s[0 + i] = Wq1 + (size_t)i * WMAT;
    ca.s[3 + i] = Wk1 + (size_t)i * WMAT;
    ca.s[6 + i] = Wv1 + (size_t)i * WMAT;
    ca.s[9 + i] = Wq2 + (size_t)i * WMAT;
    ca.s[12 + i] = Wk2 + (size_t)i * WMAT;
    ca.s[15 + i] = Wv2 + (size_t)i * WMAT;
  }
  ca.s[18] = out1_w;
  ca.s[19] = out2_w;
  cast_kernel<<<5120, 256, 0, stream>>>(ca, wb);

  TokArgs ta;
  ta.x[0] = x1; ta.x[1] = x2;
  ta.tf[0] = t1f; ta.tf[1] = t2f;
  ta.tb[0] = t1b; ta.tb[1] = t2b;
  tok_kernel<<<dim3(49, 16, 8), dim3(32, 8), 0, stream>>>(ta);

  AttnArgs aa;
  aa.q[0] = q1b; aa.q[1] = q2b;
  aa.k[0] = k1b; aa.k[1] = k2b;
  aa.v[0] = v1b; aa.v[1] = v2b;
  aa.tf[0] = t1f; aa.tf[1] = t2f;
  aa.tb[0] = t1b; aa.tb[1] = t2b;

  for (int i = 0; i < 3; i++) {
    ln_kernel<<<2 * MROWS, 64, 0, stream>>>(t1f, t2f,
        ln1_g + i * 512, ln1_b + i * 512, ln2_g + i * 512, ln2_b + i * 512,
        l1b, l2b);
    ProjArgs pa;
    pa.A0[0] = l1b; pa.W0[0] = wb + (0 + i) * WMAT; pa.b0[0] = bq1 + i * 512; pa.o0[0] = q1b;
    pa.A0[1] = t2b; pa.W0[1] = wb + (3 + i) * WMAT; pa.b0[1] = bk1 + i * 512; pa.o0[1] = k1b;
    pa.A0[2] = l2b; pa.W0[2] = wb + (9 + i) * WMAT; pa.b0[2] = bq2 + i * 512; pa.o0[2] = q2b;
    pa.A0[3] = t1b; pa.W0[3] = wb + (12 + i) * WMAT; pa.b0[3] = bk2 + i * 512; pa.o0[3] = k2b;
    pa.scl0[0] = CEXP; pa.scl0[1] = 1.f; pa.scl0[2] = CEXP; pa.scl0[3] = 1.f;
    pa.W2[0] = wb + (6 + i) * WMAT; pa.B2[0] = t2b; pa.b2[0] = bv1 + i * 512; pa.o2[0] = v1b;
    pa.W2[1] = wb + (15 + i) * WMAT; pa.B2[1] = t1b; pa.b2[1] = bv2 + i * 512; pa.o2[1] = v2b;
    proj_kernel<<<1200, 256, 0, stream>>>(pa);
    attn_kernel<<<832, 256, 0, stream>>>(aa);
  }

  float* out = (float*)d_out;
  head_kernel<<<dim3(13, 4, 8), 256, 0, stream>>>(
      wb + 18 * WMAT, wb + 19 * WMAT, t1b, t2b,
      out1_b, out2_b, bn1_g, bn1_b, bn2_g, bn2_b, out);
}